// Round 7
// baseline (438.719 us; speedup 1.0000x reference)
//
#include <hip/hip_runtime.h>
#include <hip/hip_bf16.h>
#include <hip/hip_cooperative_groups.h>
#include <math.h>

namespace cg = cooperative_groups;

// Problem constants
#define BB 2
#define HH 64
#define WW 64
#define CC 128
#define NHD 4
#define HD 32
#define KS 7
#define KK 49
#define HID 512
#define NT (BB*HH*WW)   // 8192 tokens

typedef __attribute__((ext_vector_type(8))) short bf16x8;
typedef __attribute__((ext_vector_type(4))) float f32x4;

// ---------------- LN row helper: one wave per row of 128 -> bf16 ----------------
__device__ __forceinline__ void ln_row(const float* __restrict__ xr, const float* __restrict__ g,
                                       const float* __restrict__ b, __hip_bfloat16* __restrict__ yr,
                                       int lane) {
    float v0 = xr[lane];
    float v1 = xr[lane + 64];
    float s = v0 + v1;
    #pragma unroll
    for (int off = 32; off > 0; off >>= 1) s += __shfl_xor(s, off);
    float mean = s * (1.0f / CC);
    float d0 = v0 - mean, d1 = v1 - mean;
    float vs = d0 * d0 + d1 * d1;
    #pragma unroll
    for (int off = 32; off > 0; off >>= 1) vs += __shfl_xor(vs, off);
    float rstd = rsqrtf(vs * (1.0f / CC) + 1e-5f);
    yr[lane]      = __float2bfloat16(d0 * rstd * g[lane]      + b[lane]);
    yr[lane + 64] = __float2bfloat16(d1 * rstd * g[lane + 64] + b[lane + 64]);
}

// ---------------- MFMA GEMM tile: 64x64 out, 4 waves (2x2), wave 32x32 ----------
template<int TK, int OUT_BF16, int DO_GELU, int HAS_RESID>
__device__ __forceinline__ void gemm_tile(const __hip_bfloat16* __restrict__ A,
                                          const __hip_bfloat16* __restrict__ Wt,
                                          const float* __restrict__ bias,
                                          const float* __restrict__ resid,
                                          void* __restrict__ out,
                                          int bx, int by, int N, int tid) {
    int wid  = tid >> 6;
    int lane = tid & 63;
    int wr = wid >> 1, wc = wid & 1;
    int m0 = bx * 64 + wr * 32;
    int n0 = by * 64 + wc * 32;
    int row = lane & 15;
    int kg  = lane >> 4;

    f32x4 acc[2][2] = {};
    #pragma unroll
    for (int kc = 0; kc < TK; kc += 128) {
        bf16x8 a[2][4], b[2][4];
        #pragma unroll
        for (int mi = 0; mi < 2; ++mi)
            #pragma unroll
            for (int t = 0; t < 4; ++t)
                a[mi][t] = *(const bf16x8*)(A + (size_t)(m0 + mi * 16 + row) * TK + kc + t * 32 + kg * 8);
        #pragma unroll
        for (int ni = 0; ni < 2; ++ni)
            #pragma unroll
            for (int t = 0; t < 4; ++t)
                b[ni][t] = *(const bf16x8*)(Wt + (size_t)(n0 + ni * 16 + row) * TK + kc + t * 32 + kg * 8);
        #pragma unroll
        for (int t = 0; t < 4; ++t)
            #pragma unroll
            for (int mi = 0; mi < 2; ++mi)
                #pragma unroll
                for (int ni = 0; ni < 2; ++ni)
                    acc[mi][ni] = __builtin_amdgcn_mfma_f32_16x16x32_bf16(a[mi][t], b[ni][t], acc[mi][ni], 0, 0, 0);
    }
    #pragma unroll
    for (int mi = 0; mi < 2; ++mi) {
        #pragma unroll
        for (int ni = 0; ni < 2; ++ni) {
            int col = n0 + ni * 16 + row;
            float bv = bias[col];
            #pragma unroll
            for (int r = 0; r < 4; ++r) {
                int rrow = m0 + mi * 16 + kg * 4 + r;
                float v = acc[mi][ni][r] + bv;
                if (DO_GELU) v = 0.5f * v * (1.0f + erff(v * 0.70710678118654752f));
                size_t off = (size_t)rrow * N + col;
                if (HAS_RESID) v += resid[off];
                if (OUT_BF16) ((__hip_bfloat16*)out)[off] = __float2bfloat16(v);
                else          ((float*)out)[off] = v;
            }
        }
    }
}

// ---------------- NAT attention for one token (4 waves = 4 heads) ---------------
__device__ __forceinline__ float4 bf4_to_f4(ushort4 u) {
    float4 f;
    f.x = __uint_as_float((unsigned)u.x << 16);
    f.y = __uint_as_float((unsigned)u.y << 16);
    f.z = __uint_as_float((unsigned)u.z << 16);
    f.w = __uint_as_float((unsigned)u.w << 16);
    return f;
}

__device__ __forceinline__ void attn_token(const __hip_bfloat16* __restrict__ qkv,
                                           const float* __restrict__ rpb,
                                           __hip_bfloat16* __restrict__ outp,
                                           int bij, int tid) {
    int h    = tid >> 6;               // wave id = head
    int lane = tid & 63;
    int kq = lane >> 3, dg = lane & 7;
    int j  = bij & (WW - 1);
    int bi = bij >> 6;
    int i  = bi & (HH - 1);
    int b  = bi >> 6;

    int si = i - 3; si = si < 0 ? 0 : (si > HH - KS ? HH - KS : si);
    int sj = j - 3; sj = sj < 0 ? 0 : (sj > WW - KS ? WW - KS : sj);
    int oi = si - i + 6;
    int oj = sj - j + 6;

    float4 q4 = bf4_to_f4(*(const ushort4*)(qkv + (size_t)bij * (3 * CC) + h * HD + dg * 4));
    const float sc = 0.17677669529663687f;  // 1/sqrt(32)
    q4.x *= sc; q4.y *= sc; q4.z *= sc; q4.w *= sc;
    const float* rpb_h = rpb + h * 169;     // 13x13

    float s[7];
    float4 v4[7];
    #pragma unroll
    for (int t = 0; t < 7; ++t) {
        int kk = t * 8 + kq;
        bool valid = kk < KK;
        int a = (kk * 37) >> 8;             // kk/7 for kk<56
        int c = kk - a * 7;
        if (!valid) { a = 0; c = 0; }
        int ki = si + a, kj = sj + c;
        const __hip_bfloat16* base = qkv + ((size_t)((b * HH + ki) * WW + kj)) * (3 * CC) + h * HD + dg * 4;
        float4 k4 = bf4_to_f4(*(const ushort4*)(base + CC));
        v4[t]     = bf4_to_f4(*(const ushort4*)(base + 2 * CC));
        float pd = q4.x * k4.x + q4.y * k4.y + q4.z * k4.z + q4.w * k4.w;
        pd += __shfl_xor(pd, 1);
        pd += __shfl_xor(pd, 2);
        pd += __shfl_xor(pd, 4);
        s[t] = valid ? (pd + rpb_h[(oi + a) * 13 + (oj + c)]) : -1e30f;
    }
    float mx = s[0];
    #pragma unroll
    for (int t = 1; t < 7; ++t) mx = fmaxf(mx, s[t]);
    mx = fmaxf(mx, __shfl_xor(mx, 8));
    mx = fmaxf(mx, __shfl_xor(mx, 16));
    mx = fmaxf(mx, __shfl_xor(mx, 32));
    float l = 0.0f;
    #pragma unroll
    for (int t = 0; t < 7; ++t) { s[t] = __expf(s[t] - mx); l += s[t]; }
    l += __shfl_xor(l, 8);
    l += __shfl_xor(l, 16);
    l += __shfl_xor(l, 32);
    float inv = 1.0f / l;

    float4 o4 = make_float4(0.f, 0.f, 0.f, 0.f);
    #pragma unroll
    for (int t = 0; t < 7; ++t) {
        o4.x += s[t] * v4[t].x;
        o4.y += s[t] * v4[t].y;
        o4.z += s[t] * v4[t].z;
        o4.w += s[t] * v4[t].w;
    }
    #pragma unroll
    for (int off = 8; off <= 32; off <<= 1) {
        o4.x += __shfl_xor(o4.x, off);
        o4.y += __shfl_xor(o4.y, off);
        o4.z += __shfl_xor(o4.z, off);
        o4.w += __shfl_xor(o4.w, off);
    }
    if (kq == 0) {
        __hip_bfloat16 r0 = __float2bfloat16(o4.x * inv);
        __hip_bfloat16 r1 = __float2bfloat16(o4.y * inv);
        __hip_bfloat16 r2 = __float2bfloat16(o4.z * inv);
        __hip_bfloat16 r3 = __float2bfloat16(o4.w * inv);
        ushort4 u;
        u.x = *(unsigned short*)&r0;
        u.y = *(unsigned short*)&r1;
        u.z = *(unsigned short*)&r2;
        u.w = *(unsigned short*)&r3;
        *(ushort4*)(outp + (size_t)bij * CC + h * HD + dg * 4) = u;
    }
}

// ---------------- THE cooperative mega-kernel -----------------------------------
__global__ void __launch_bounds__(256, 4)
fused_all(const float* __restrict__ x,
          const float* __restrict__ n1g, const float* __restrict__ n1b,
          const float* __restrict__ qkv_w, const float* __restrict__ qkv_b,
          const float* __restrict__ rpb,
          const float* __restrict__ proj_w, const float* __restrict__ proj_b,
          const float* __restrict__ n2g, const float* __restrict__ n2b,
          const float* __restrict__ fc1_w, const float* __restrict__ fc1_b,
          const float* __restrict__ fc2_w, const float* __restrict__ fc2_b,
          float* __restrict__ out, char* __restrict__ ws) {
    cg::grid_group grid = cg::this_grid();
    const int tid = threadIdx.x;
    const int nb  = gridDim.x;

    // workspace layout (same as R5)
    __hip_bfloat16* qkv  = (__hip_bfloat16*)(ws);
    __hip_bfloat16* h1   = (__hip_bfloat16*)(ws);            // reuses qkv region
    __hip_bfloat16* xn   = (__hip_bfloat16*)(ws + 12582912);
    __hip_bfloat16* attn = (__hip_bfloat16*)(ws + 14680064);
    float* x1            = (float*)(ws + 16777216);
    __hip_bfloat16* y    = (__hip_bfloat16*)(ws + 20971520);
    __hip_bfloat16* qkv_wt  = (__hip_bfloat16*)(ws + 23068672);  // 384x128
    __hip_bfloat16* proj_wt = qkv_wt + 384 * 128;                // 128x128
    __hip_bfloat16* fc1_wt  = proj_wt + 128 * 128;               // 512x128
    __hip_bfloat16* fc2_wt  = fc1_wt + 512 * 128;                // 128x512

    // ---- P0: weight cast/transpose (768 units) + LN1 (2048 units of 4 rows) ----
    for (int u = blockIdx.x; u < 768 + 2048; u += nb) {
        if (u < 768) {
            int idx = u * 256 + tid;
            const float* W; __hip_bfloat16* Wt; int K, N, off;
            if (idx < 49152)       { W = qkv_w;  Wt = qkv_wt;  K = 128; N = 384; off = idx; }
            else if (idx < 65536)  { W = proj_w; Wt = proj_wt; K = 128; N = 128; off = idx - 49152; }
            else if (idx < 131072) { W = fc1_w;  Wt = fc1_wt;  K = 128; N = 512; off = idx - 65536; }
            else                   { W = fc2_w;  Wt = fc2_wt;  K = 512; N = 128; off = idx - 131072; }
            int k = off / N, n = off - k * N;
            Wt[(size_t)n * K + k] = __float2bfloat16(W[(size_t)k * N + n]);
        } else {
            int row = (u - 768) * 4 + (tid >> 6);
            ln_row(x + (size_t)row * CC, n1g, n1b, xn + (size_t)row * CC, tid & 63);
        }
    }
    grid.sync();
    // ---- P1: QKV GEMM (8192x128)@(128x384) -> bf16 qkv; 128x6 tiles ----
    for (int u = blockIdx.x; u < 128 * 6; u += nb)
        gemm_tile<128, 1, 0, 0>(xn, qkv_wt, qkv_b, nullptr, qkv, u & 127, u >> 7, 384, tid);
    grid.sync();
    // ---- P2: NAT attention; 8192 token units ----
    for (int u = blockIdx.x; u < NT; u += nb)
        attn_token(qkv, rpb, attn, u, tid);
    grid.sync();
    // ---- P3: proj + bias + residual(x) -> f32 x1; 128x2 tiles ----
    for (int u = blockIdx.x; u < 128 * 2; u += nb)
        gemm_tile<128, 0, 0, 1>(attn, proj_wt, proj_b, x, x1, u & 127, u >> 7, 128, tid);
    grid.sync();
    // ---- P4: LN2 -> bf16 y; 2048 units of 4 rows ----
    for (int u = blockIdx.x; u < 2048; u += nb) {
        int row = u * 4 + (tid >> 6);
        ln_row(x1 + (size_t)row * CC, n2g, n2b, y + (size_t)row * CC, tid & 63);
    }
    grid.sync();
    // ---- P5: FC1 + gelu -> bf16 h1; 128x8 tiles ----
    for (int u = blockIdx.x; u < 128 * 8; u += nb)
        gemm_tile<128, 1, 1, 0>(y, fc1_wt, fc1_b, nullptr, h1, u & 127, u >> 7, 512, tid);
    grid.sync();
    // ---- P6: FC2 + bias + residual(x1) -> f32 out; 128x2 tiles ----
    for (int u = blockIdx.x; u < 128 * 2; u += nb)
        gemm_tile<512, 0, 0, 1>(h1, fc2_wt, fc2_b, x1, out, u & 127, u >> 7, 128, tid);
}

extern "C" void kernel_launch(void* const* d_in, const int* in_sizes, int n_in,
                              void* d_out, int out_size, void* d_ws, size_t ws_size,
                              hipStream_t stream) {
    const float* x       = (const float*)d_in[0];
    const float* norm1_g = (const float*)d_in[1];
    const float* norm1_b = (const float*)d_in[2];
    const float* qkv_w   = (const float*)d_in[3];
    const float* qkv_b   = (const float*)d_in[4];
    const float* rpb     = (const float*)d_in[5];
    const float* proj_w  = (const float*)d_in[6];
    const float* proj_b  = (const float*)d_in[7];
    const float* norm2_g = (const float*)d_in[8];
    const float* norm2_b = (const float*)d_in[9];
    const float* fc1_w   = (const float*)d_in[10];
    const float* fc1_b   = (const float*)d_in[11];
    const float* fc2_w   = (const float*)d_in[12];
    const float* fc2_b   = (const float*)d_in[13];
    float* out = (float*)d_out;
    char* ws = (char*)d_ws;

    int maxb = 0;
    hipOccupancyMaxActiveBlocksPerMultiprocessor(&maxb, fused_all, 256, 0);
    if (maxb < 1) maxb = 1;
    int nblocks = maxb * 256;
    if (nblocks > 2048) nblocks = 2048;

    void* args[] = {
        (void*)&x, (void*)&norm1_g, (void*)&norm1_b,
        (void*)&qkv_w, (void*)&qkv_b, (void*)&rpb,
        (void*)&proj_w, (void*)&proj_b,
        (void*)&norm2_g, (void*)&norm2_b,
        (void*)&fc1_w, (void*)&fc1_b,
        (void*)&fc2_w, (void*)&fc2_b,
        (void*)&out, (void*)&ws,
    };
    hipLaunchCooperativeKernel((void*)fused_all, dim3(nblocks), dim3(256),
                               args, 0, stream);
}

// Round 8
// 63.303 us; speedup vs baseline: 6.9304x; 6.9304x over previous
//
#include <hip/hip_runtime.h>
#include <hip/hip_bf16.h>
#include <math.h>

// Problem constants
#define BB 2
#define HH 64
#define WW 64
#define CC 128
#define NHD 4
#define HD 32
#define KS 7
#define KK 49
#define HID 512
#define NT (BB*HH*WW)   // 8192 tokens

typedef __attribute__((ext_vector_type(8))) short bf16x8;
typedef __attribute__((ext_vector_type(4))) float f32x4;

__device__ __forceinline__ short f2bs(float v) {
    __hip_bfloat16 h = __float2bfloat16(v);
    return *reinterpret_cast<short*>(&h);
}
__device__ __forceinline__ float4 bf4_to_f4(ushort4 u) {
    float4 f;
    f.x = __uint_as_float((unsigned)u.x << 16);
    f.y = __uint_as_float((unsigned)u.y << 16);
    f.z = __uint_as_float((unsigned)u.z << 16);
    f.w = __uint_as_float((unsigned)u.w << 16);
    return f;
}

// ---------------- prep: weight cast/transpose W[K][N] f32 -> Wt[N][K] bf16 ------
__global__ void prep_cast(const float* __restrict__ qkv_w, const float* __restrict__ proj_w,
                          const float* __restrict__ fc1_w, const float* __restrict__ fc2_w,
                          __hip_bfloat16* __restrict__ qkv_wt, __hip_bfloat16* __restrict__ proj_wt,
                          __hip_bfloat16* __restrict__ fc1_wt, __hip_bfloat16* __restrict__ fc2_wt) {
    int idx = blockIdx.x * 256 + threadIdx.x;
    const float* W; __hip_bfloat16* Wt; int K, N, off;
    if (idx < 49152)       { W = qkv_w;  Wt = qkv_wt;  K = 128; N = 384; off = idx; }
    else if (idx < 65536)  { W = proj_w; Wt = proj_wt; K = 128; N = 128; off = idx - 49152; }
    else if (idx < 131072) { W = fc1_w;  Wt = fc1_wt;  K = 128; N = 512; off = idx - 65536; }
    else                   { W = fc2_w;  Wt = fc2_wt;  K = 512; N = 128; off = idx - 131072; }
    int k = off / N, n = off - k * N;
    Wt[(size_t)n * K + k] = __float2bfloat16(W[(size_t)k * N + n]);
}

// ---------------- LN1 + QKV GEMM: 16 rows/block, full N=384 ---------------------
// Phase 1: LN of 16 rows into swizzled bf16 LDS; Phase 2: 4 waves x 96 cols MFMA.
__global__ void __launch_bounds__(256, 2)
qkv_ln_kernel(const float* __restrict__ x, const float* __restrict__ g,
              const float* __restrict__ bta, const __hip_bfloat16* __restrict__ qkv_wt,
              const float* __restrict__ qkv_b, __hip_bfloat16* __restrict__ qkv) {
    __shared__ bf16x8 ys[16 * 16];
    int tid = threadIdx.x;
    int R0 = blockIdx.x * 16;

    { // LN1: thread = (row = tid>>4, seg = tid&15), 8 f32 each
        int row = tid >> 4, seg = tid & 15;
        const float* xr = x + (size_t)(R0 + row) * CC + seg * 8;
        float4 a0 = ((const float4*)xr)[0];
        float4 a1 = ((const float4*)xr)[1];
        float s1 = a0.x + a0.y + a0.z + a0.w + a1.x + a1.y + a1.z + a1.w;
        float s2 = a0.x*a0.x + a0.y*a0.y + a0.z*a0.z + a0.w*a0.w
                 + a1.x*a1.x + a1.y*a1.y + a1.z*a1.z + a1.w*a1.w;
        #pragma unroll
        for (int off = 1; off <= 8; off <<= 1) { s1 += __shfl_xor(s1, off); s2 += __shfl_xor(s2, off); }
        float mean = s1 * (1.0f / CC);
        float var  = s2 * (1.0f / CC) - mean * mean;
        float rstd = rsqrtf(var + 1e-5f);
        float4 g0 = *(const float4*)(g + seg * 8);
        float4 g1 = *(const float4*)(g + seg * 8 + 4);
        float4 b0 = *(const float4*)(bta + seg * 8);
        float4 b1 = *(const float4*)(bta + seg * 8 + 4);
        bf16x8 ch;
        ch[0] = f2bs((a0.x - mean) * rstd * g0.x + b0.x);
        ch[1] = f2bs((a0.y - mean) * rstd * g0.y + b0.y);
        ch[2] = f2bs((a0.z - mean) * rstd * g0.z + b0.z);
        ch[3] = f2bs((a0.w - mean) * rstd * g0.w + b0.w);
        ch[4] = f2bs((a1.x - mean) * rstd * g1.x + b1.x);
        ch[5] = f2bs((a1.y - mean) * rstd * g1.y + b1.y);
        ch[6] = f2bs((a1.z - mean) * rstd * g1.z + b1.z);
        ch[7] = f2bs((a1.w - mean) * rstd * g1.w + b1.w);
        ys[row * 16 + (seg ^ row)] = ch;
    }
    __syncthreads();

    int wid = tid >> 6, lane = tid & 63;
    int rowf = lane & 15, kg = lane >> 4;
    int n0 = wid * 96;

    bf16x8 a[4];
    #pragma unroll
    for (int t = 0; t < 4; ++t) a[t] = ys[rowf * 16 + ((t * 4 + kg) ^ rowf)];

    f32x4 acc[6] = {};
    #pragma unroll
    for (int nf = 0; nf < 6; ++nf) {
        int col = n0 + nf * 16 + rowf;
        bf16x8 bfr[4];
        #pragma unroll
        for (int t = 0; t < 4; ++t)
            bfr[t] = *(const bf16x8*)(qkv_wt + (size_t)col * CC + t * 32 + kg * 8);
        #pragma unroll
        for (int t = 0; t < 4; ++t)
            acc[nf] = __builtin_amdgcn_mfma_f32_16x16x32_bf16(a[t], bfr[t], acc[nf], 0, 0, 0);
    }
    #pragma unroll
    for (int nf = 0; nf < 6; ++nf) {
        int col = n0 + nf * 16 + rowf;
        float bv = qkv_b[col];
        #pragma unroll
        for (int r = 0; r < 4; ++r) {
            int row = kg * 4 + r;
            qkv[(size_t)(R0 + row) * 384 + col] = __float2bfloat16(acc[nf][r] + bv);
        }
    }
}

// ---------------- NAT attention: one WAVE per (token, head) ---------------------
__global__ void nat_attn_wave8(const __hip_bfloat16* __restrict__ qkv,
                               const float* __restrict__ rpb,
                               __hip_bfloat16* __restrict__ out) {
    int h    = threadIdx.x >> 6;
    int lane = threadIdx.x & 63;
    int kq = lane >> 3, dg = lane & 7;
    int bij = blockIdx.x;
    int j  = bij & (WW - 1);
    int bi = bij >> 6;
    int i  = bi & (HH - 1);
    int b  = bi >> 6;

    int si = i - 3; si = si < 0 ? 0 : (si > HH - KS ? HH - KS : si);
    int sj = j - 3; sj = sj < 0 ? 0 : (sj > WW - KS ? WW - KS : sj);
    int oi = si - i + 6;
    int oj = sj - j + 6;

    float4 q4 = bf4_to_f4(*(const ushort4*)(qkv + (size_t)bij * (3 * CC) + h * HD + dg * 4));
    const float sc = 0.17677669529663687f;  // 1/sqrt(32)
    q4.x *= sc; q4.y *= sc; q4.z *= sc; q4.w *= sc;
    const float* rpb_h = rpb + h * 169;

    float s[7];
    float4 v4[7];
    #pragma unroll
    for (int t = 0; t < 7; ++t) {
        int kk = t * 8 + kq;
        bool valid = kk < KK;
        int a = (kk * 37) >> 8;
        int c = kk - a * 7;
        if (!valid) { a = 0; c = 0; }
        int ki = si + a, kj = sj + c;
        const __hip_bfloat16* base = qkv + ((size_t)((b * HH + ki) * WW + kj)) * (3 * CC) + h * HD + dg * 4;
        float4 k4 = bf4_to_f4(*(const ushort4*)(base + CC));
        v4[t]     = bf4_to_f4(*(const ushort4*)(base + 2 * CC));
        float pd = q4.x * k4.x + q4.y * k4.y + q4.z * k4.z + q4.w * k4.w;
        pd += __shfl_xor(pd, 1);
        pd += __shfl_xor(pd, 2);
        pd += __shfl_xor(pd, 4);
        s[t] = valid ? (pd + rpb_h[(oi + a) * 13 + (oj + c)]) : -1e30f;
    }
    float mx = s[0];
    #pragma unroll
    for (int t = 1; t < 7; ++t) mx = fmaxf(mx, s[t]);
    mx = fmaxf(mx, __shfl_xor(mx, 8));
    mx = fmaxf(mx, __shfl_xor(mx, 16));
    mx = fmaxf(mx, __shfl_xor(mx, 32));
    float l = 0.0f;
    #pragma unroll
    for (int t = 0; t < 7; ++t) { s[t] = __expf(s[t] - mx); l += s[t]; }
    l += __shfl_xor(l, 8);
    l += __shfl_xor(l, 16);
    l += __shfl_xor(l, 32);
    float inv = 1.0f / l;

    float4 o4 = make_float4(0.f, 0.f, 0.f, 0.f);
    #pragma unroll
    for (int t = 0; t < 7; ++t) {
        o4.x += s[t] * v4[t].x;
        o4.y += s[t] * v4[t].y;
        o4.z += s[t] * v4[t].z;
        o4.w += s[t] * v4[t].w;
    }
    #pragma unroll
    for (int off = 8; off <= 32; off <<= 1) {
        o4.x += __shfl_xor(o4.x, off);
        o4.y += __shfl_xor(o4.y, off);
        o4.z += __shfl_xor(o4.z, off);
        o4.w += __shfl_xor(o4.w, off);
    }
    if (kq == 0) {
        __hip_bfloat16 r0 = __float2bfloat16(o4.x * inv);
        __hip_bfloat16 r1 = __float2bfloat16(o4.y * inv);
        __hip_bfloat16 r2 = __float2bfloat16(o4.z * inv);
        __hip_bfloat16 r3 = __float2bfloat16(o4.w * inv);
        ushort4 u;
        u.x = *(unsigned short*)&r0;
        u.y = *(unsigned short*)&r1;
        u.z = *(unsigned short*)&r2;
        u.w = *(unsigned short*)&r3;
        *(ushort4*)(out + (size_t)bij * CC + h * HD + dg * 4) = u;
    }
}

// ---------------- TAIL: proj(+resid) -> LN2 -> FC1+gelu -> FC2(+resid) ----------
// 16 rows per block; x1, y, h1 all live in LDS only. 4 waves.
#define X1P 132          // x1s row stride (f32)
#define H1P 520          // h1s row stride (bf16)
__global__ void __launch_bounds__(256, 2)
tail_kernel(const __hip_bfloat16* __restrict__ attn, const float* __restrict__ x,
            const __hip_bfloat16* __restrict__ proj_wt, const float* __restrict__ proj_b,
            const float* __restrict__ n2g, const float* __restrict__ n2b,
            const __hip_bfloat16* __restrict__ fc1_wt, const float* __restrict__ fc1_b,
            const __hip_bfloat16* __restrict__ fc2_wt, const float* __restrict__ fc2_b,
            float* __restrict__ out) {
    __shared__ float x1s[16 * X1P];
    __shared__ bf16x8 ysb[16 * 16];
    __shared__ short h1s[16 * H1P];
    int tid = threadIdx.x;
    int R0 = blockIdx.x * 16;
    int wid = tid >> 6, lane = tid & 63;
    int rowf = lane & 15, kg = lane >> 4;

    // ---- proj: wave w covers cols w*32..+32, K=128 from global attn ----
    {
        bf16x8 a[4];
        #pragma unroll
        for (int t = 0; t < 4; ++t)
            a[t] = *(const bf16x8*)(attn + (size_t)(R0 + rowf) * CC + t * 32 + kg * 8);
        int n0 = wid * 32;
        f32x4 acc[2] = {};
        #pragma unroll
        for (int ni = 0; ni < 2; ++ni) {
            int col = n0 + ni * 16 + rowf;
            bf16x8 bfr[4];
            #pragma unroll
            for (int t = 0; t < 4; ++t)
                bfr[t] = *(const bf16x8*)(proj_wt + (size_t)col * CC + t * 32 + kg * 8);
            #pragma unroll
            for (int t = 0; t < 4; ++t)
                acc[ni] = __builtin_amdgcn_mfma_f32_16x16x32_bf16(a[t], bfr[t], acc[ni], 0, 0, 0);
        }
        #pragma unroll
        for (int ni = 0; ni < 2; ++ni) {
            int col = n0 + ni * 16 + rowf;
            float bv = proj_b[col];
            #pragma unroll
            for (int r = 0; r < 4; ++r) {
                int row = kg * 4 + r;
                x1s[row * X1P + col] = acc[ni][r] + bv + x[(size_t)(R0 + row) * CC + col];
            }
        }
    }
    __syncthreads();

    // ---- LN2: thread = (row, seg) ----
    {
        int row = tid >> 4, seg = tid & 15;
        float4 a0 = *(const float4*)&x1s[row * X1P + seg * 8];
        float4 a1 = *(const float4*)&x1s[row * X1P + seg * 8 + 4];
        float s1 = a0.x + a0.y + a0.z + a0.w + a1.x + a1.y + a1.z + a1.w;
        float s2 = a0.x*a0.x + a0.y*a0.y + a0.z*a0.z + a0.w*a0.w
                 + a1.x*a1.x + a1.y*a1.y + a1.z*a1.z + a1.w*a1.w;
        #pragma unroll
        for (int off = 1; off <= 8; off <<= 1) { s1 += __shfl_xor(s1, off); s2 += __shfl_xor(s2, off); }
        float mean = s1 * (1.0f / CC);
        float var  = s2 * (1.0f / CC) - mean * mean;
        float rstd = rsqrtf(var + 1e-5f);
        float4 g0 = *(const float4*)(n2g + seg * 8);
        float4 g1 = *(const float4*)(n2g + seg * 8 + 4);
        float4 b0 = *(const float4*)(n2b + seg * 8);
        float4 b1 = *(const float4*)(n2b + seg * 8 + 4);
        bf16x8 ch;
        ch[0] = f2bs((a0.x - mean) * rstd * g0.x + b0.x);
        ch[1] = f2bs((a0.y - mean) * rstd * g0.y + b0.y);
        ch[2] = f2bs((a0.z - mean) * rstd * g0.z + b0.z);
        ch[3] = f2bs((a0.w - mean) * rstd * g0.w + b0.w);
        ch[4] = f2bs((a1.x - mean) * rstd * g1.x + b1.x);
        ch[5] = f2bs((a1.y - mean) * rstd * g1.y + b1.y);
        ch[6] = f2bs((a1.z - mean) * rstd * g1.z + b1.z);
        ch[7] = f2bs((a1.w - mean) * rstd * g1.w + b1.w);
        ysb[row * 16 + (seg ^ row)] = ch;
    }
    __syncthreads();

    // ---- FC1 + gelu: wave w covers h1 cols w*128..+128 ----
    {
        bf16x8 a[4];
        #pragma unroll
        for (int t = 0; t < 4; ++t) a[t] = ysb[rowf * 16 + ((t * 4 + kg) ^ rowf)];
        int n0 = wid * 128;
        f32x4 acc8[8] = {};
        #pragma unroll
        for (int half = 0; half < 2; ++half) {
            bf16x8 bfr[4][4];
            #pragma unroll
            for (int nf2 = 0; nf2 < 4; ++nf2) {
                int col = n0 + (half * 4 + nf2) * 16 + rowf;
                #pragma unroll
                for (int t = 0; t < 4; ++t)
                    bfr[nf2][t] = *(const bf16x8*)(fc1_wt + (size_t)col * CC + t * 32 + kg * 8);
            }
            #pragma unroll
            for (int nf2 = 0; nf2 < 4; ++nf2)
                #pragma unroll
                for (int t = 0; t < 4; ++t)
                    acc8[half * 4 + nf2] = __builtin_amdgcn_mfma_f32_16x16x32_bf16(a[t], bfr[nf2][t], acc8[half * 4 + nf2], 0, 0, 0);
        }
        #pragma unroll
        for (int nf = 0; nf < 8; ++nf) {
            int col = n0 + nf * 16 + rowf;
            float bv = fc1_b[col];
            #pragma unroll
            for (int r = 0; r < 4; ++r) {
                int row = kg * 4 + r;
                float v = acc8[nf][r] + bv;
                v = 0.5f * v * (1.0f + erff(v * 0.70710678118654752f));
                h1s[row * H1P + col] = f2bs(v);
            }
        }
    }
    __syncthreads();

    // ---- FC2 + resid: wave w covers out cols w*32..+32, K=512 from LDS ----
    {
        int n0 = wid * 32;
        f32x4 acc[2] = {};
        #pragma unroll
        for (int kc = 0; kc < 512; kc += 128) {
            bf16x8 a[4];
            #pragma unroll
            for (int t = 0; t < 4; ++t)
                a[t] = *(const bf16x8*)&h1s[rowf * H1P + kc + t * 32 + kg * 8];
            #pragma unroll
            for (int ni = 0; ni < 2; ++ni) {
                int col = n0 + ni * 16 + rowf;
                bf16x8 bfr[4];
                #pragma unroll
                for (int t = 0; t < 4; ++t)
                    bfr[t] = *(const bf16x8*)(fc2_wt + (size_t)col * HID + kc + t * 32 + kg * 8);
                #pragma unroll
                for (int t = 0; t < 4; ++t)
                    acc[ni] = __builtin_amdgcn_mfma_f32_16x16x32_bf16(a[t], bfr[t], acc[ni], 0, 0, 0);
            }
        }
        #pragma unroll
        for (int ni = 0; ni < 2; ++ni) {
            int col = n0 + ni * 16 + rowf;
            float bv = fc2_b[col];
            #pragma unroll
            for (int r = 0; r < 4; ++r) {
                int row = kg * 4 + r;
                out[(size_t)(R0 + row) * CC + col] = acc[ni][r] + bv + x1s[row * X1P + col];
            }
        }
    }
}

extern "C" void kernel_launch(void* const* d_in, const int* in_sizes, int n_in,
                              void* d_out, int out_size, void* d_ws, size_t ws_size,
                              hipStream_t stream) {
    const float* x       = (const float*)d_in[0];
    const float* norm1_g = (const float*)d_in[1];
    const float* norm1_b = (const float*)d_in[2];
    const float* qkv_w   = (const float*)d_in[3];
    const float* qkv_b   = (const float*)d_in[4];
    const float* rpb     = (const float*)d_in[5];
    const float* proj_w  = (const float*)d_in[6];
    const float* proj_b  = (const float*)d_in[7];
    const float* norm2_g = (const float*)d_in[8];
    const float* norm2_b = (const float*)d_in[9];
    const float* fc1_w   = (const float*)d_in[10];
    const float* fc1_b   = (const float*)d_in[11];
    const float* fc2_w   = (const float*)d_in[12];
    const float* fc2_b   = (const float*)d_in[13];
    float* out = (float*)d_out;
    char* ws = (char*)d_ws;

    // workspace: qkv bf16 [0, 6291456); attn bf16 [6291456, 8388608); wts at 8388608
    __hip_bfloat16* qkv  = (__hip_bfloat16*)(ws);
    __hip_bfloat16* attn = (__hip_bfloat16*)(ws + 6291456);
    __hip_bfloat16* qkv_wt  = (__hip_bfloat16*)(ws + 8388608);  // 384x128
    __hip_bfloat16* proj_wt = qkv_wt + 384 * 128;               // 128x128
    __hip_bfloat16* fc1_wt  = proj_wt + 128 * 128;              // 512x128
    __hip_bfloat16* fc2_wt  = fc1_wt + 512 * 128;               // 128x512

    prep_cast<<<768, 256, 0, stream>>>(qkv_w, proj_w, fc1_w, fc2_w,
                                       qkv_wt, proj_wt, fc1_wt, fc2_wt);
    qkv_ln_kernel<<<NT / 16, 256, 0, stream>>>(x, norm1_g, norm1_b, qkv_wt, qkv_b, qkv);
    nat_attn_wave8<<<NT, 256, 0, stream>>>(qkv, rpb, attn);
    tail_kernel<<<NT / 16, 256, 0, stream>>>(attn, x, proj_wt, proj_b, norm2_g, norm2_b,
                                             fc1_wt, fc1_b, fc2_wt, fc2_b, out);
}

// Round 9
// 62.259 us; speedup vs baseline: 7.0467x; 1.0168x over previous
//
#include <hip/hip_runtime.h>
#include <hip/hip_bf16.h>
#include <math.h>

// Problem constants
#define BB 2
#define HH 64
#define WW 64
#define CC 128
#define NHD 4
#define HD 32
#define KS 7
#define KK 49
#define HID 512
#define NT (BB*HH*WW)   // 8192 tokens

typedef __attribute__((ext_vector_type(8))) short bf16x8;
typedef __attribute__((ext_vector_type(4))) float f32x4;

__device__ __forceinline__ short f2bs(float v) {
    __hip_bfloat16 h = __float2bfloat16(v);
    return *reinterpret_cast<short*>(&h);
}
__device__ __forceinline__ float4 bf4_to_f4(ushort4 u) {
    float4 f;
    f.x = __uint_as_float((unsigned)u.x << 16);
    f.y = __uint_as_float((unsigned)u.y << 16);
    f.z = __uint_as_float((unsigned)u.z << 16);
    f.w = __uint_as_float((unsigned)u.w << 16);
    return f;
}

// ---------------- prep: weight cast/transpose W[K][N] f32 -> Wt[N][K] bf16 ------
__global__ void prep_cast(const float* __restrict__ qkv_w, const float* __restrict__ proj_w,
                          const float* __restrict__ fc1_w, const float* __restrict__ fc2_w,
                          __hip_bfloat16* __restrict__ qkv_wt, __hip_bfloat16* __restrict__ proj_wt,
                          __hip_bfloat16* __restrict__ fc1_wt, __hip_bfloat16* __restrict__ fc2_wt) {
    int idx = blockIdx.x * 256 + threadIdx.x;
    const float* W; __hip_bfloat16* Wt; int K, N, off;
    if (idx < 49152)       { W = qkv_w;  Wt = qkv_wt;  K = 128; N = 384; off = idx; }
    else if (idx < 65536)  { W = proj_w; Wt = proj_wt; K = 128; N = 128; off = idx - 49152; }
    else if (idx < 131072) { W = fc1_w;  Wt = fc1_wt;  K = 128; N = 512; off = idx - 65536; }
    else                   { W = fc2_w;  Wt = fc2_wt;  K = 512; N = 128; off = idx - 131072; }
    int k = off / N, n = off - k * N;
    Wt[(size_t)n * K + k] = __float2bfloat16(W[(size_t)k * N + n]);
}

// ---------------- LN1 + QKV GEMM: 16 rows/block, 8 waves (48 cols each) ---------
__global__ void __launch_bounds__(512, 4)
qkv_ln_kernel(const float* __restrict__ x, const float* __restrict__ g,
              const float* __restrict__ bta, const __hip_bfloat16* __restrict__ qkv_wt,
              const float* __restrict__ qkv_b, __hip_bfloat16* __restrict__ qkv) {
    __shared__ ushort4 ys4[16 * 32];    // 16 rows x 16 chunks(16B) swizzled, as 8B halves
    int tid = threadIdx.x;
    int R0 = blockIdx.x * 16;

    { // LN1: 32 threads per row, 4 f32 each
        int row = tid >> 5, t32 = tid & 31;
        const float* xr = x + (size_t)(R0 + row) * CC + t32 * 4;
        float4 a0 = *(const float4*)xr;
        float s1 = a0.x + a0.y + a0.z + a0.w;
        float s2 = a0.x*a0.x + a0.y*a0.y + a0.z*a0.z + a0.w*a0.w;
        #pragma unroll
        for (int off = 1; off <= 16; off <<= 1) { s1 += __shfl_xor(s1, off); s2 += __shfl_xor(s2, off); }
        float mean = s1 * (1.0f / CC);
        float var  = s2 * (1.0f / CC) - mean * mean;
        float rstd = rsqrtf(var + 1e-5f);
        float4 g0 = *(const float4*)(g + t32 * 4);
        float4 b0 = *(const float4*)(bta + t32 * 4);
        ushort4 ch;
        ch.x = (unsigned short)f2bs((a0.x - mean) * rstd * g0.x + b0.x);
        ch.y = (unsigned short)f2bs((a0.y - mean) * rstd * g0.y + b0.y);
        ch.z = (unsigned short)f2bs((a0.z - mean) * rstd * g0.z + b0.z);
        ch.w = (unsigned short)f2bs((a0.w - mean) * rstd * g0.w + b0.w);
        int c = t32 >> 1;
        ys4[row * 32 + ((c ^ row) << 1) + (t32 & 1)] = ch;
    }
    __syncthreads();

    const bf16x8* ys8 = (const bf16x8*)ys4;
    int wid = tid >> 6, lane = tid & 63;
    int rowf = lane & 15, kg = lane >> 4;
    int n0 = wid * 48;

    bf16x8 a[4];
    #pragma unroll
    for (int t = 0; t < 4; ++t) a[t] = ys8[rowf * 16 + ((t * 4 + kg) ^ rowf)];

    f32x4 acc[3] = {};
    #pragma unroll
    for (int nf = 0; nf < 3; ++nf) {
        int col = n0 + nf * 16 + rowf;
        bf16x8 bfr[4];
        #pragma unroll
        for (int t = 0; t < 4; ++t)
            bfr[t] = *(const bf16x8*)(qkv_wt + (size_t)col * CC + t * 32 + kg * 8);
        #pragma unroll
        for (int t = 0; t < 4; ++t)
            acc[nf] = __builtin_amdgcn_mfma_f32_16x16x32_bf16(a[t], bfr[t], acc[nf], 0, 0, 0);
    }
    #pragma unroll
    for (int nf = 0; nf < 3; ++nf) {
        int col = n0 + nf * 16 + rowf;
        float bv = qkv_b[col];
        #pragma unroll
        for (int r = 0; r < 4; ++r) {
            int row = kg * 4 + r;
            qkv[(size_t)(R0 + row) * 384 + col] = __float2bfloat16(acc[nf][r] + bv);
        }
    }
}

// ---------------- NAT attention: one WAVE per (token, head) ---------------------
__global__ void nat_attn_wave8(const __hip_bfloat16* __restrict__ qkv,
                               const float* __restrict__ rpb,
                               __hip_bfloat16* __restrict__ out) {
    int h    = threadIdx.x >> 6;
    int lane = threadIdx.x & 63;
    int kq = lane >> 3, dg = lane & 7;
    int bij = blockIdx.x;
    int j  = bij & (WW - 1);
    int bi = bij >> 6;
    int i  = bi & (HH - 1);
    int b  = bi >> 6;

    int si = i - 3; si = si < 0 ? 0 : (si > HH - KS ? HH - KS : si);
    int sj = j - 3; sj = sj < 0 ? 0 : (sj > WW - KS ? WW - KS : sj);
    int oi = si - i + 6;
    int oj = sj - j + 6;

    float4 q4 = bf4_to_f4(*(const ushort4*)(qkv + (size_t)bij * (3 * CC) + h * HD + dg * 4));
    const float sc = 0.17677669529663687f;  // 1/sqrt(32)
    q4.x *= sc; q4.y *= sc; q4.z *= sc; q4.w *= sc;
    const float* rpb_h = rpb + h * 169;

    float s[7];
    float4 v4[7];
    #pragma unroll
    for (int t = 0; t < 7; ++t) {
        int kk = t * 8 + kq;
        bool valid = kk < KK;
        int a = (kk * 37) >> 8;
        int c = kk - a * 7;
        if (!valid) { a = 0; c = 0; }
        int ki = si + a, kj = sj + c;
        const __hip_bfloat16* base = qkv + ((size_t)((b * HH + ki) * WW + kj)) * (3 * CC) + h * HD + dg * 4;
        float4 k4 = bf4_to_f4(*(const ushort4*)(base + CC));
        v4[t]     = bf4_to_f4(*(const ushort4*)(base + 2 * CC));
        float pd = q4.x * k4.x + q4.y * k4.y + q4.z * k4.z + q4.w * k4.w;
        pd += __shfl_xor(pd, 1);
        pd += __shfl_xor(pd, 2);
        pd += __shfl_xor(pd, 4);
        s[t] = valid ? (pd + rpb_h[(oi + a) * 13 + (oj + c)]) : -1e30f;
    }
    float mx = s[0];
    #pragma unroll
    for (int t = 1; t < 7; ++t) mx = fmaxf(mx, s[t]);
    mx = fmaxf(mx, __shfl_xor(mx, 8));
    mx = fmaxf(mx, __shfl_xor(mx, 16));
    mx = fmaxf(mx, __shfl_xor(mx, 32));
    float l = 0.0f;
    #pragma unroll
    for (int t = 0; t < 7; ++t) { s[t] = __expf(s[t] - mx); l += s[t]; }
    l += __shfl_xor(l, 8);
    l += __shfl_xor(l, 16);
    l += __shfl_xor(l, 32);
    float inv = 1.0f / l;

    float4 o4 = make_float4(0.f, 0.f, 0.f, 0.f);
    #pragma unroll
    for (int t = 0; t < 7; ++t) {
        o4.x += s[t] * v4[t].x;
        o4.y += s[t] * v4[t].y;
        o4.z += s[t] * v4[t].z;
        o4.w += s[t] * v4[t].w;
    }
    #pragma unroll
    for (int off = 8; off <= 32; off <<= 1) {
        o4.x += __shfl_xor(o4.x, off);
        o4.y += __shfl_xor(o4.y, off);
        o4.z += __shfl_xor(o4.z, off);
        o4.w += __shfl_xor(o4.w, off);
    }
    if (kq == 0) {
        __hip_bfloat16 r0 = __float2bfloat16(o4.x * inv);
        __hip_bfloat16 r1 = __float2bfloat16(o4.y * inv);
        __hip_bfloat16 r2 = __float2bfloat16(o4.z * inv);
        __hip_bfloat16 r3 = __float2bfloat16(o4.w * inv);
        ushort4 u;
        u.x = *(unsigned short*)&r0;
        u.y = *(unsigned short*)&r1;
        u.z = *(unsigned short*)&r2;
        u.w = *(unsigned short*)&r3;
        *(ushort4*)(out + (size_t)bij * CC + h * HD + dg * 4) = u;
    }
}

// ---------------- TAIL: proj(+resid) -> LN2 -> FC1+gelu -> FC2(+resid) ----------
// 16 rows per block, 8 waves; x1, y, h1 live only in LDS.
#define X1P 132          // x1s row stride (f32)
#define H1P 520          // h1s row stride (bf16)
__global__ void __launch_bounds__(512, 4)
tail_kernel(const __hip_bfloat16* __restrict__ attn, const float* __restrict__ x,
            const __hip_bfloat16* __restrict__ proj_wt, const float* __restrict__ proj_b,
            const float* __restrict__ n2g, const float* __restrict__ n2b,
            const __hip_bfloat16* __restrict__ fc1_wt, const float* __restrict__ fc1_b,
            const __hip_bfloat16* __restrict__ fc2_wt, const float* __restrict__ fc2_b,
            float* __restrict__ out) {
    __shared__ float x1s[16 * X1P];
    __shared__ ushort4 ys4[16 * 32];
    __shared__ short h1s[16 * H1P];
    int tid = threadIdx.x;
    int R0 = blockIdx.x * 16;
    int wid = tid >> 6, lane = tid & 63;
    int rowf = lane & 15, kg = lane >> 4;

    // ---- proj: wave w covers 16 cols (w*16), K=128 from global attn ----
    {
        bf16x8 a[4];
        #pragma unroll
        for (int t = 0; t < 4; ++t)
            a[t] = *(const bf16x8*)(attn + (size_t)(R0 + rowf) * CC + t * 32 + kg * 8);
        int col = wid * 16 + rowf;
        bf16x8 bfr[4];
        #pragma unroll
        for (int t = 0; t < 4; ++t)
            bfr[t] = *(const bf16x8*)(proj_wt + (size_t)col * CC + t * 32 + kg * 8);
        f32x4 acc = {};
        #pragma unroll
        for (int t = 0; t < 4; ++t)
            acc = __builtin_amdgcn_mfma_f32_16x16x32_bf16(a[t], bfr[t], acc, 0, 0, 0);
        float bv = proj_b[col];
        #pragma unroll
        for (int r = 0; r < 4; ++r) {
            int row = kg * 4 + r;
            x1s[row * X1P + col] = acc[r] + bv + x[(size_t)(R0 + row) * CC + col];
        }
    }
    __syncthreads();

    // ---- LN2: 32 threads per row ----
    {
        int row = tid >> 5, t32 = tid & 31;
        float4 a0 = *(const float4*)&x1s[row * X1P + t32 * 4];
        float s1 = a0.x + a0.y + a0.z + a0.w;
        float s2 = a0.x*a0.x + a0.y*a0.y + a0.z*a0.z + a0.w*a0.w;
        #pragma unroll
        for (int off = 1; off <= 16; off <<= 1) { s1 += __shfl_xor(s1, off); s2 += __shfl_xor(s2, off); }
        float mean = s1 * (1.0f / CC);
        float var  = s2 * (1.0f / CC) - mean * mean;
        float rstd = rsqrtf(var + 1e-5f);
        float4 g0 = *(const float4*)(n2g + t32 * 4);
        float4 b0 = *(const float4*)(n2b + t32 * 4);
        ushort4 ch;
        ch.x = (unsigned short)f2bs((a0.x - mean) * rstd * g0.x + b0.x);
        ch.y = (unsigned short)f2bs((a0.y - mean) * rstd * g0.y + b0.y);
        ch.z = (unsigned short)f2bs((a0.z - mean) * rstd * g0.z + b0.z);
        ch.w = (unsigned short)f2bs((a0.w - mean) * rstd * g0.w + b0.w);
        int c = t32 >> 1;
        ys4[row * 32 + ((c ^ row) << 1) + (t32 & 1)] = ch;
    }
    __syncthreads();

    const bf16x8* ys8 = (const bf16x8*)ys4;
    // ---- FC1 + gelu: wave w covers 64 cols (w*64) ----
    {
        bf16x8 a[4];
        #pragma unroll
        for (int t = 0; t < 4; ++t) a[t] = ys8[rowf * 16 + ((t * 4 + kg) ^ rowf)];
        int n0 = wid * 64;
        f32x4 acc4[4] = {};
        #pragma unroll
        for (int nf = 0; nf < 4; ++nf) {
            int col = n0 + nf * 16 + rowf;
            bf16x8 bfr[4];
            #pragma unroll
            for (int t = 0; t < 4; ++t)
                bfr[t] = *(const bf16x8*)(fc1_wt + (size_t)col * CC + t * 32 + kg * 8);
            #pragma unroll
            for (int t = 0; t < 4; ++t)
                acc4[nf] = __builtin_amdgcn_mfma_f32_16x16x32_bf16(a[t], bfr[t], acc4[nf], 0, 0, 0);
        }
        #pragma unroll
        for (int nf = 0; nf < 4; ++nf) {
            int col = n0 + nf * 16 + rowf;
            float bv = fc1_b[col];
            #pragma unroll
            for (int r = 0; r < 4; ++r) {
                int row = kg * 4 + r;
                float v = acc4[nf][r] + bv;
                v = 0.5f * v * (1.0f + erff(v * 0.70710678118654752f));
                h1s[row * H1P + col] = f2bs(v);
            }
        }
    }
    __syncthreads();

    // ---- FC2 + resid: wave w covers 16 cols (w*16), K=512 from LDS ----
    {
        int col = wid * 16 + rowf;
        f32x4 acc = {};
        #pragma unroll
        for (int kc = 0; kc < 512; kc += 128) {
            bf16x8 a[4], bfr[4];
            #pragma unroll
            for (int t = 0; t < 4; ++t)
                a[t] = *(const bf16x8*)&h1s[rowf * H1P + kc + t * 32 + kg * 8];
            #pragma unroll
            for (int t = 0; t < 4; ++t)
                bfr[t] = *(const bf16x8*)(fc2_wt + (size_t)col * HID + kc + t * 32 + kg * 8);
            #pragma unroll
            for (int t = 0; t < 4; ++t)
                acc = __builtin_amdgcn_mfma_f32_16x16x32_bf16(a[t], bfr[t], acc, 0, 0, 0);
        }
        float bv = fc2_b[col];
        #pragma unroll
        for (int r = 0; r < 4; ++r) {
            int row = kg * 4 + r;
            out[(size_t)(R0 + row) * CC + col] = acc[r] + bv + x1s[row * X1P + col];
        }
    }
}

extern "C" void kernel_launch(void* const* d_in, const int* in_sizes, int n_in,
                              void* d_out, int out_size, void* d_ws, size_t ws_size,
                              hipStream_t stream) {
    const float* x       = (const float*)d_in[0];
    const float* norm1_g = (const float*)d_in[1];
    const float* norm1_b = (const float*)d_in[2];
    const float* qkv_w   = (const float*)d_in[3];
    const float* qkv_b   = (const float*)d_in[4];
    const float* rpb     = (const float*)d_in[5];
    const float* proj_w  = (const float*)d_in[6];
    const float* proj_b  = (const float*)d_in[7];
    const float* norm2_g = (const float*)d_in[8];
    const float* norm2_b = (const float*)d_in[9];
    const float* fc1_w   = (const float*)d_in[10];
    const float* fc1_b   = (const float*)d_in[11];
    const float* fc2_w   = (const float*)d_in[12];
    const float* fc2_b   = (const float*)d_in[13];
    float* out = (float*)d_out;
    char* ws = (char*)d_ws;

    // workspace: qkv bf16 [0, 6291456); attn bf16 [6291456, 8388608); wts at 8388608
    __hip_bfloat16* qkv  = (__hip_bfloat16*)(ws);
    __hip_bfloat16* attn = (__hip_bfloat16*)(ws + 6291456);
    __hip_bfloat16* qkv_wt  = (__hip_bfloat16*)(ws + 8388608);  // 384x128
    __hip_bfloat16* proj_wt = qkv_wt + 384 * 128;               // 128x128
    __hip_bfloat16* fc1_wt  = proj_wt + 128 * 128;              // 512x128
    __hip_bfloat16* fc2_wt  = fc1_wt + 512 * 128;               // 128x512

    prep_cast<<<768, 256, 0, stream>>>(qkv_w, proj_w, fc1_w, fc2_w,
                                       qkv_wt, proj_wt, fc1_wt, fc2_wt);
    qkv_ln_kernel<<<NT / 16, 512, 0, stream>>>(x, norm1_g, norm1_b, qkv_wt, qkv_b, qkv);
    nat_attn_wave8<<<NT, 256, 0, stream>>>(qkv, rpb, attn);
    tail_kernel<<<NT / 16, 512, 0, stream>>>(attn, x, proj_wt, proj_b, norm2_g, norm2_b,
                                             fc1_wt, fc1_b, fc2_wt, fc2_b, out);
}

// Round 10
// 59.183 us; speedup vs baseline: 7.4129x; 1.0520x over previous
//
#include <hip/hip_runtime.h>
#include <hip/hip_bf16.h>
#include <math.h>

// Problem constants
#define BB 2
#define HH 64
#define WW 64
#define CC 128
#define NHD 4
#define HD 32
#define KS 7
#define KK 49
#define HID 512
#define NT (BB*HH*WW)   // 8192 tokens

typedef __attribute__((ext_vector_type(8))) short bf16x8;
typedef __attribute__((ext_vector_type(4))) float f32x4;

__device__ __forceinline__ short f2bs(float v) {
    __hip_bfloat16 h = __float2bfloat16(v);
    return *reinterpret_cast<short*>(&h);
}
__device__ __forceinline__ float4 bf4_to_f4(ushort4 u) {
    float4 f;
    f.x = __uint_as_float((unsigned)u.x << 16);
    f.y = __uint_as_float((unsigned)u.y << 16);
    f.z = __uint_as_float((unsigned)u.z << 16);
    f.w = __uint_as_float((unsigned)u.w << 16);
    return f;
}

// ---------------- prep: weight cast/transpose W[K][N] f32 -> Wt[N][K] bf16 ------
__global__ void prep_cast(const float* __restrict__ qkv_w, const float* __restrict__ proj_w,
                          const float* __restrict__ fc1_w, const float* __restrict__ fc2_w,
                          __hip_bfloat16* __restrict__ qkv_wt, __hip_bfloat16* __restrict__ proj_wt,
                          __hip_bfloat16* __restrict__ fc1_wt, __hip_bfloat16* __restrict__ fc2_wt) {
    int idx = blockIdx.x * 256 + threadIdx.x;
    const float* W; __hip_bfloat16* Wt; int K, N, off;
    if (idx < 49152)       { W = qkv_w;  Wt = qkv_wt;  K = 128; N = 384; off = idx; }
    else if (idx < 65536)  { W = proj_w; Wt = proj_wt; K = 128; N = 128; off = idx - 49152; }
    else if (idx < 131072) { W = fc1_w;  Wt = fc1_wt;  K = 128; N = 512; off = idx - 65536; }
    else                   { W = fc2_w;  Wt = fc2_wt;  K = 512; N = 128; off = idx - 131072; }
    int k = off / N, n = off - k * N;
    Wt[(size_t)n * K + k] = __float2bfloat16(W[(size_t)k * N + n]);
}

// ---------------- LN1 + QKV GEMM: 16 rows/block, 8 waves (48 cols each) ---------
// Output head-major: qb/kb/vb [h][token][32] bf16.
__global__ void __launch_bounds__(512, 4)
qkv_ln_kernel(const float* __restrict__ x, const float* __restrict__ g,
              const float* __restrict__ bta, const __hip_bfloat16* __restrict__ qkv_wt,
              const float* __restrict__ qkv_b,
              __hip_bfloat16* __restrict__ qb, __hip_bfloat16* __restrict__ kb,
              __hip_bfloat16* __restrict__ vb) {
    __shared__ ushort4 ys4[16 * 32];    // 16 rows x 16 chunks(16B) swizzled, as 8B halves
    int tid = threadIdx.x;
    int R0 = blockIdx.x * 16;

    { // LN1: 32 threads per row, 4 f32 each
        int row = tid >> 5, t32 = tid & 31;
        const float* xr = x + (size_t)(R0 + row) * CC + t32 * 4;
        float4 a0 = *(const float4*)xr;
        float s1 = a0.x + a0.y + a0.z + a0.w;
        float s2 = a0.x*a0.x + a0.y*a0.y + a0.z*a0.z + a0.w*a0.w;
        #pragma unroll
        for (int off = 1; off <= 16; off <<= 1) { s1 += __shfl_xor(s1, off); s2 += __shfl_xor(s2, off); }
        float mean = s1 * (1.0f / CC);
        float var  = s2 * (1.0f / CC) - mean * mean;
        float rstd = rsqrtf(var + 1e-5f);
        float4 g0 = *(const float4*)(g + t32 * 4);
        float4 b0 = *(const float4*)(bta + t32 * 4);
        ushort4 ch;
        ch.x = (unsigned short)f2bs((a0.x - mean) * rstd * g0.x + b0.x);
        ch.y = (unsigned short)f2bs((a0.y - mean) * rstd * g0.y + b0.y);
        ch.z = (unsigned short)f2bs((a0.z - mean) * rstd * g0.z + b0.z);
        ch.w = (unsigned short)f2bs((a0.w - mean) * rstd * g0.w + b0.w);
        int c = t32 >> 1;
        ys4[row * 32 + ((c ^ row) << 1) + (t32 & 1)] = ch;
    }
    __syncthreads();

    const bf16x8* ys8 = (const bf16x8*)ys4;
    int wid = tid >> 6, lane = tid & 63;
    int rowf = lane & 15, kg = lane >> 4;
    int n0 = wid * 48;

    bf16x8 a[4];
    #pragma unroll
    for (int t = 0; t < 4; ++t) a[t] = ys8[rowf * 16 + ((t * 4 + kg) ^ rowf)];

    f32x4 acc[3] = {};
    #pragma unroll
    for (int nf = 0; nf < 3; ++nf) {
        int col = n0 + nf * 16 + rowf;
        bf16x8 bfr[4];
        #pragma unroll
        for (int t = 0; t < 4; ++t)
            bfr[t] = *(const bf16x8*)(qkv_wt + (size_t)col * CC + t * 32 + kg * 8);
        #pragma unroll
        for (int t = 0; t < 4; ++t)
            acc[nf] = __builtin_amdgcn_mfma_f32_16x16x32_bf16(a[t], bfr[t], acc[nf], 0, 0, 0);
    }
    #pragma unroll
    for (int nf = 0; nf < 3; ++nf) {
        int col = n0 + nf * 16 + rowf;
        int which = col >> 7;           // 0=q,1=k,2=v  (wave-uniform per nf)
        int h = (col >> 5) & 3;
        int d = col & 31;
        __hip_bfloat16* dst = which == 0 ? qb : (which == 1 ? kb : vb);
        float bv = qkv_b[col];
        #pragma unroll
        for (int r = 0; r < 4; ++r) {
            int row = kg * 4 + r;
            dst[((size_t)h * NT + (R0 + row)) * HD + d] = __float2bfloat16(acc[nf][r] + bv);
        }
    }
}

// ---------------- MEGA TAIL: attn -> proj(+resid) -> LN2 -> FC1+gelu -> FC2(+resid)
// 16 tokens per block, 8 waves; attn out, x1, y, h1 all live only in LDS.
#define X1P 132          // x1s row stride (f32)
#define H1P 520          // h1s row stride (bf16)
__global__ void __launch_bounds__(512, 4)
mega_tail(const __hip_bfloat16* __restrict__ qb, const __hip_bfloat16* __restrict__ kb,
          const __hip_bfloat16* __restrict__ vb, const float* __restrict__ rpb,
          const float* __restrict__ x,
          const __hip_bfloat16* __restrict__ proj_wt, const float* __restrict__ proj_b,
          const float* __restrict__ n2g, const float* __restrict__ n2b,
          const __hip_bfloat16* __restrict__ fc1_wt, const float* __restrict__ fc1_b,
          const __hip_bfloat16* __restrict__ fc2_wt, const float* __restrict__ fc2_b,
          float* __restrict__ out) {
    __shared__ float rpbs[NHD * 169];   // 2.7 KB
    __shared__ ushort4 ysA4[16 * 32];   // 4 KB: attn out, later reused for LN2 out
    __shared__ float x1s[16 * X1P];     // 8.4 KB
    __shared__ short h1s[16 * H1P];     // 16.6 KB
    int tid = threadIdx.x;
    int R0 = blockIdx.x * 16;
    int wid = tid >> 6, lane = tid & 63;
    int rowf = lane & 15, kg = lane >> 4;

    // stage rpb into LDS
    for (int idx = tid; idx < NHD * 169; idx += 512) rpbs[idx] = rpb[idx];
    __syncthreads();

    // ---- Phase A: attention; wave wid handles 8 (token,head) units -------------
    {
        int kq = lane >> 3, dg = lane & 7;
        const float scq = 0.17677669529663687f;  // 1/sqrt(32)
        for (int s = 0; s < 8; ++s) {
            int u = wid * 8 + s;
            int lt = u >> 2, h = u & 3;
            int bij = R0 + lt;
            int j  = bij & (WW - 1);
            int bi = bij >> 6;
            int i  = bi & (HH - 1);
            int b  = bi >> 6;
            int si = i - 3; si = si < 0 ? 0 : (si > HH - KS ? HH - KS : si);
            int sj = j - 3; sj = sj < 0 ? 0 : (sj > WW - KS ? WW - KS : sj);
            int oi = si - i + 6, oj = sj - j + 6;

            float4 q4 = bf4_to_f4(*(const ushort4*)(qb + ((size_t)h * NT + bij) * HD + dg * 4));
            q4.x *= scq; q4.y *= scq; q4.z *= scq; q4.w *= scq;
            const float* rpb_h = rpbs + h * 169;

            float sv[7];
            float4 v4[7];
            #pragma unroll
            for (int t = 0; t < 7; ++t) {
                int kk = t * 8 + kq;
                bool valid = kk < KK;
                int a = (kk * 37) >> 8;         // kk/7 for kk<56
                int c = kk - a * 7;
                if (!valid) { a = 0; c = 0; }
                int tok = (b * HH + si + a) * WW + sj + c;
                float4 k4 = bf4_to_f4(*(const ushort4*)(kb + ((size_t)h * NT + tok) * HD + dg * 4));
                v4[t]     = bf4_to_f4(*(const ushort4*)(vb + ((size_t)h * NT + tok) * HD + dg * 4));
                float pd = q4.x * k4.x + q4.y * k4.y + q4.z * k4.z + q4.w * k4.w;
                pd += __shfl_xor(pd, 1);
                pd += __shfl_xor(pd, 2);
                pd += __shfl_xor(pd, 4);
                sv[t] = valid ? (pd + rpb_h[(oi + a) * 13 + (oj + c)]) : -1e30f;
            }
            float mx = sv[0];
            #pragma unroll
            for (int t = 1; t < 7; ++t) mx = fmaxf(mx, sv[t]);
            mx = fmaxf(mx, __shfl_xor(mx, 8));
            mx = fmaxf(mx, __shfl_xor(mx, 16));
            mx = fmaxf(mx, __shfl_xor(mx, 32));
            float l = 0.0f;
            #pragma unroll
            for (int t = 0; t < 7; ++t) { sv[t] = __expf(sv[t] - mx); l += sv[t]; }
            l += __shfl_xor(l, 8);
            l += __shfl_xor(l, 16);
            l += __shfl_xor(l, 32);
            float inv = 1.0f / l;

            float4 o4 = make_float4(0.f, 0.f, 0.f, 0.f);
            #pragma unroll
            for (int t = 0; t < 7; ++t) {
                o4.x += sv[t] * v4[t].x;
                o4.y += sv[t] * v4[t].y;
                o4.z += sv[t] * v4[t].z;
                o4.w += sv[t] * v4[t].w;
            }
            #pragma unroll
            for (int off = 8; off <= 32; off <<= 1) {
                o4.x += __shfl_xor(o4.x, off);
                o4.y += __shfl_xor(o4.y, off);
                o4.z += __shfl_xor(o4.z, off);
                o4.w += __shfl_xor(o4.w, off);
            }
            if (kq == 0) {
                ushort4 u4;
                u4.x = (unsigned short)f2bs(o4.x * inv);
                u4.y = (unsigned short)f2bs(o4.y * inv);
                u4.z = (unsigned short)f2bs(o4.z * inv);
                u4.w = (unsigned short)f2bs(o4.w * inv);
                int c = h * 4 + (dg >> 1);
                ysA4[lt * 32 + ((c ^ lt) << 1) + (dg & 1)] = u4;
            }
        }
    }
    __syncthreads();

    // ---- Phase B: proj (wave w covers 16 cols), K=128 from LDS attn tile -------
    {
        const bf16x8* ysA8 = (const bf16x8*)ysA4;
        bf16x8 a[4];
        #pragma unroll
        for (int t = 0; t < 4; ++t)
            a[t] = ysA8[rowf * 16 + ((t * 4 + kg) ^ rowf)];
        int col = wid * 16 + rowf;
        bf16x8 bfr[4];
        #pragma unroll
        for (int t = 0; t < 4; ++t)
            bfr[t] = *(const bf16x8*)(proj_wt + (size_t)col * CC + t * 32 + kg * 8);
        f32x4 acc = {};
        #pragma unroll
        for (int t = 0; t < 4; ++t)
            acc = __builtin_amdgcn_mfma_f32_16x16x32_bf16(a[t], bfr[t], acc, 0, 0, 0);
        float bv = proj_b[col];
        #pragma unroll
        for (int r = 0; r < 4; ++r) {
            int row = kg * 4 + r;
            x1s[row * X1P + col] = acc[r] + bv + x[(size_t)(R0 + row) * CC + col];
        }
    }
    __syncthreads();

    // ---- Phase C: LN2 (32 threads/row) -> ysA4 (reused) ------------------------
    {
        int row = tid >> 5, t32 = tid & 31;
        float4 a0 = *(const float4*)&x1s[row * X1P + t32 * 4];
        float s1 = a0.x + a0.y + a0.z + a0.w;
        float s2 = a0.x*a0.x + a0.y*a0.y + a0.z*a0.z + a0.w*a0.w;
        #pragma unroll
        for (int off = 1; off <= 16; off <<= 1) { s1 += __shfl_xor(s1, off); s2 += __shfl_xor(s2, off); }
        float mean = s1 * (1.0f / CC);
        float var  = s2 * (1.0f / CC) - mean * mean;
        float rstd = rsqrtf(var + 1e-5f);
        float4 g0 = *(const float4*)(n2g + t32 * 4);
        float4 b0 = *(const float4*)(n2b + t32 * 4);
        ushort4 ch;
        ch.x = (unsigned short)f2bs((a0.x - mean) * rstd * g0.x + b0.x);
        ch.y = (unsigned short)f2bs((a0.y - mean) * rstd * g0.y + b0.y);
        ch.z = (unsigned short)f2bs((a0.z - mean) * rstd * g0.z + b0.z);
        ch.w = (unsigned short)f2bs((a0.w - mean) * rstd * g0.w + b0.w);
        int c = t32 >> 1;
        ysA4[row * 32 + ((c ^ row) << 1) + (t32 & 1)] = ch;
    }
    __syncthreads();

    // ---- Phase D: FC1 + gelu (wave w covers 64 cols) ---------------------------
    {
        const bf16x8* ys8 = (const bf16x8*)ysA4;
        bf16x8 a[4];
        #pragma unroll
        for (int t = 0; t < 4; ++t) a[t] = ys8[rowf * 16 + ((t * 4 + kg) ^ rowf)];
        int n0 = wid * 64;
        f32x4 acc4[4] = {};
        #pragma unroll
        for (int nf = 0; nf < 4; ++nf) {
            int col = n0 + nf * 16 + rowf;
            bf16x8 bfr[4];
            #pragma unroll
            for (int t = 0; t < 4; ++t)
                bfr[t] = *(const bf16x8*)(fc1_wt + (size_t)col * CC + t * 32 + kg * 8);
            #pragma unroll
            for (int t = 0; t < 4; ++t)
                acc4[nf] = __builtin_amdgcn_mfma_f32_16x16x32_bf16(a[t], bfr[t], acc4[nf], 0, 0, 0);
        }
        #pragma unroll
        for (int nf = 0; nf < 4; ++nf) {
            int col = n0 + nf * 16 + rowf;
            float bv = fc1_b[col];
            #pragma unroll
            for (int r = 0; r < 4; ++r) {
                int row = kg * 4 + r;
                float v = acc4[nf][r] + bv;
                v = 0.5f * v * (1.0f + erff(v * 0.70710678118654752f));
                h1s[row * H1P + col] = f2bs(v);
            }
        }
    }
    __syncthreads();

    // ---- Phase E: FC2 + resid (wave w covers 16 cols), K=512 from LDS ----------
    {
        int col = wid * 16 + rowf;
        f32x4 acc = {};
        #pragma unroll
        for (int kc = 0; kc < 512; kc += 128) {
            bf16x8 a[4], bfr[4];
            #pragma unroll
            for (int t = 0; t < 4; ++t)
                a[t] = *(const bf16x8*)&h1s[rowf * H1P + kc + t * 32 + kg * 8];
            #pragma unroll
            for (int t = 0; t < 4; ++t)
                bfr[t] = *(const bf16x8*)(fc2_wt + (size_t)col * HID + kc + t * 32 + kg * 8);
            #pragma unroll
            for (int t = 0; t < 4; ++t)
                acc = __builtin_amdgcn_mfma_f32_16x16x32_bf16(a[t], bfr[t], acc, 0, 0, 0);
        }
        float bv = fc2_b[col];
        #pragma unroll
        for (int r = 0; r < 4; ++r) {
            int row = kg * 4 + r;
            out[(size_t)(R0 + row) * CC + col] = acc[r] + bv + x1s[row * X1P + col];
        }
    }
}

extern "C" void kernel_launch(void* const* d_in, const int* in_sizes, int n_in,
                              void* d_out, int out_size, void* d_ws, size_t ws_size,
                              hipStream_t stream) {
    const float* x       = (const float*)d_in[0];
    const float* norm1_g = (const float*)d_in[1];
    const float* norm1_b = (const float*)d_in[2];
    const float* qkv_w   = (const float*)d_in[3];
    const float* qkv_b   = (const float*)d_in[4];
    const float* rpb     = (const float*)d_in[5];
    const float* proj_w  = (const float*)d_in[6];
    const float* proj_b  = (const float*)d_in[7];
    const float* norm2_g = (const float*)d_in[8];
    const float* norm2_b = (const float*)d_in[9];
    const float* fc1_w   = (const float*)d_in[10];
    const float* fc1_b   = (const float*)d_in[11];
    const float* fc2_w   = (const float*)d_in[12];
    const float* fc2_b   = (const float*)d_in[13];
    float* out = (float*)d_out;
    char* ws = (char*)d_ws;

    // workspace: qb/kb/vb bf16 head-major [4][8192][32] = 2 MB each; weights after
    __hip_bfloat16* qb = (__hip_bfloat16*)(ws);
    __hip_bfloat16* kb = (__hip_bfloat16*)(ws + 2097152);
    __hip_bfloat16* vb = (__hip_bfloat16*)(ws + 4194304);
    __hip_bfloat16* qkv_wt  = (__hip_bfloat16*)(ws + 6291456);  // 384x128
    __hip_bfloat16* proj_wt = qkv_wt + 384 * 128;               // 128x128
    __hip_bfloat16* fc1_wt  = proj_wt + 128 * 128;              // 512x128
    __hip_bfloat16* fc2_wt  = fc1_wt + 512 * 128;               // 128x512

    prep_cast<<<768, 256, 0, stream>>>(qkv_w, proj_w, fc1_w, fc2_w,
                                       qkv_wt, proj_wt, fc1_wt, fc2_wt);
    qkv_ln_kernel<<<NT / 16, 512, 0, stream>>>(x, norm1_g, norm1_b, qkv_wt, qkv_b,
                                               qb, kb, vb);
    mega_tail<<<NT / 16, 512, 0, stream>>>(qb, kb, vb, rpb, x, proj_wt, proj_b,
                                           norm2_g, norm2_b, fc1_wt, fc1_b,
                                           fc2_wt, fc2_b, out);
}

// Round 11
// 53.741 us; speedup vs baseline: 8.1636x; 1.1013x over previous
//
#include <hip/hip_runtime.h>
#include <hip/hip_bf16.h>
#include <math.h>

// Problem constants
#define BB 2
#define HH 64
#define WW 64
#define CC 128
#define NHD 4
#define HD 32
#define KS 7
#define KK 49
#define HID 512
#define NT (BB*HH*WW)   // 8192 tokens

typedef __attribute__((ext_vector_type(8))) short bf16x8;
typedef __attribute__((ext_vector_type(4))) short bf16x4;
typedef __attribute__((ext_vector_type(4))) float f32x4;

__device__ __forceinline__ short f2bs(float v) {
    __hip_bfloat16 h = __float2bfloat16(v);
    return *reinterpret_cast<short*>(&h);
}

__device__ __forceinline__ f32x4 mfma16(bf16x4 a, bf16x4 b, f32x4 c) {
#if __has_builtin(__builtin_amdgcn_mfma_f32_16x16x16bf16_1k)
    return __builtin_amdgcn_mfma_f32_16x16x16bf16_1k(a, b, c, 0, 0, 0);
#else
    asm("v_mfma_f32_16x16x16_bf16 %0, %1, %2, %0" : "+v"(c) : "v"(a), "v"(b));
    return c;
#endif
}

// ---------------- prep: weight cast/transpose W[K][N] f32 -> Wt[N][K] bf16 ------
__global__ void prep_cast(const float* __restrict__ qkv_w, const float* __restrict__ proj_w,
                          const float* __restrict__ fc1_w, const float* __restrict__ fc2_w,
                          __hip_bfloat16* __restrict__ qkv_wt, __hip_bfloat16* __restrict__ proj_wt,
                          __hip_bfloat16* __restrict__ fc1_wt, __hip_bfloat16* __restrict__ fc2_wt) {
    int idx = blockIdx.x * 256 + threadIdx.x;
    const float* W; __hip_bfloat16* Wt; int K, N, off;
    if (idx < 49152)       { W = qkv_w;  Wt = qkv_wt;  K = 128; N = 384; off = idx; }
    else if (idx < 65536)  { W = proj_w; Wt = proj_wt; K = 128; N = 128; off = idx - 49152; }
    else if (idx < 131072) { W = fc1_w;  Wt = fc1_wt;  K = 128; N = 512; off = idx - 65536; }
    else                   { W = fc2_w;  Wt = fc2_wt;  K = 512; N = 128; off = idx - 131072; }
    int k = off / N, n = off - k * N;
    Wt[(size_t)n * K + k] = __float2bfloat16(W[(size_t)k * N + n]);
}

// ---------------- LN1 + QKV GEMM: 16 rows/block, 8 waves (48 cols each) ---------
// q,k: token-major [h][tok][32]; v: d-major vbT[h*32+d][tok].
__global__ void __launch_bounds__(512, 4)
qkv_ln_kernel(const float* __restrict__ x, const float* __restrict__ g,
              const float* __restrict__ bta, const __hip_bfloat16* __restrict__ qkv_wt,
              const float* __restrict__ qkv_b,
              __hip_bfloat16* __restrict__ qb, __hip_bfloat16* __restrict__ kb,
              __hip_bfloat16* __restrict__ vbT) {
    __shared__ ushort4 ys4[16 * 32];
    int tid = threadIdx.x;
    int R0 = blockIdx.x * 16;

    { // LN1: 32 threads per row, 4 f32 each
        int row = tid >> 5, t32 = tid & 31;
        const float* xr = x + (size_t)(R0 + row) * CC + t32 * 4;
        float4 a0 = *(const float4*)xr;
        float s1 = a0.x + a0.y + a0.z + a0.w;
        float s2 = a0.x*a0.x + a0.y*a0.y + a0.z*a0.z + a0.w*a0.w;
        #pragma unroll
        for (int off = 1; off <= 16; off <<= 1) { s1 += __shfl_xor(s1, off); s2 += __shfl_xor(s2, off); }
        float mean = s1 * (1.0f / CC);
        float var  = s2 * (1.0f / CC) - mean * mean;
        float rstd = rsqrtf(var + 1e-5f);
        float4 g0 = *(const float4*)(g + t32 * 4);
        float4 b0 = *(const float4*)(bta + t32 * 4);
        ushort4 ch;
        ch.x = (unsigned short)f2bs((a0.x - mean) * rstd * g0.x + b0.x);
        ch.y = (unsigned short)f2bs((a0.y - mean) * rstd * g0.y + b0.y);
        ch.z = (unsigned short)f2bs((a0.z - mean) * rstd * g0.z + b0.z);
        ch.w = (unsigned short)f2bs((a0.w - mean) * rstd * g0.w + b0.w);
        int c = t32 >> 1;
        ys4[row * 32 + ((c ^ row) << 1) + (t32 & 1)] = ch;
    }
    __syncthreads();

    const bf16x8* ys8 = (const bf16x8*)ys4;
    int wid = tid >> 6, lane = tid & 63;
    int rowf = lane & 15, kg = lane >> 4;
    int n0 = wid * 48;

    bf16x8 a[4];
    #pragma unroll
    for (int t = 0; t < 4; ++t) a[t] = ys8[rowf * 16 + ((t * 4 + kg) ^ rowf)];

    f32x4 acc[3] = {};
    #pragma unroll
    for (int nf = 0; nf < 3; ++nf) {
        int col = n0 + nf * 16 + rowf;
        bf16x8 bfr[4];
        #pragma unroll
        for (int t = 0; t < 4; ++t)
            bfr[t] = *(const bf16x8*)(qkv_wt + (size_t)col * CC + t * 32 + kg * 8);
        #pragma unroll
        for (int t = 0; t < 4; ++t)
            acc[nf] = __builtin_amdgcn_mfma_f32_16x16x32_bf16(a[t], bfr[t], acc[nf], 0, 0, 0);
    }
    #pragma unroll
    for (int nf = 0; nf < 3; ++nf) {
        int col = n0 + nf * 16 + rowf;
        int which = col >> 7;           // 0=q,1=k,2=v (wave-uniform)
        int h = (col >> 5) & 3;
        int d = col & 31;
        float bv = qkv_b[col];
        if (which == 2) {
            ushort4 u;
            u.x = (unsigned short)f2bs(acc[nf][0] + bv);
            u.y = (unsigned short)f2bs(acc[nf][1] + bv);
            u.z = (unsigned short)f2bs(acc[nf][2] + bv);
            u.w = (unsigned short)f2bs(acc[nf][3] + bv);
            *(ushort4*)(vbT + ((size_t)(h * 32 + d) * NT + R0 + kg * 4)) = u;
        } else {
            __hip_bfloat16* dst = which == 0 ? qb : kb;
            #pragma unroll
            for (int r = 0; r < 4; ++r)
                dst[((size_t)h * NT + (R0 + kg * 4 + r)) * HD + d] = __float2bfloat16(acc[nf][r] + bv);
        }
    }
}

// ---------------- MEGA TAIL: MFMA attn -> proj(+resid) -> LN2 -> FC1+gelu -> FC2 --
#define X1P 132          // x1s row stride (f32)
#define H1P 520          // h1s row stride (bf16)
__global__ void __launch_bounds__(512, 4)
mega_tail(const __hip_bfloat16* __restrict__ qb, const __hip_bfloat16* __restrict__ kb,
          const __hip_bfloat16* __restrict__ vbT, const float* __restrict__ rpb,
          const float* __restrict__ x,
          const __hip_bfloat16* __restrict__ proj_wt, const float* __restrict__ proj_b,
          const float* __restrict__ n2g, const float* __restrict__ n2b,
          const __hip_bfloat16* __restrict__ fc1_wt, const float* __restrict__ fc1_b,
          const __hip_bfloat16* __restrict__ fc2_wt, const float* __restrict__ fc2_b,
          float* __restrict__ out) {
    __shared__ float rpbs[720];         // 16-offset + 4*169 + pad; pre-scaled by log2e
    __shared__ ushort4 ysA4[16 * 32];   // attn out, reused for LN2 out
    __shared__ float x1s[16 * X1P];
    __shared__ short h1s[16 * H1P];
    int tid = threadIdx.x;
    int R0 = blockIdx.x * 16;
    int wid = tid >> 6, lane = tid & 63;
    int rowf = lane & 15, kg = lane >> 4;

    for (int idx = tid; idx < NHD * 169; idx += 512) rpbs[16 + idx] = rpb[idx] * 1.4426950408889634f;
    __syncthreads();

    // ---- Phase A: MFMA attention; wave h (0..3) does head h for all 16 tokens ----
    if (wid < 4) {
        const int h = wid;
        const int q  = rowf;            // query index / key_local / d_local
        // geometry (wave-uniform except per-q)
        int j0 = R0 & 63;
        int i  = (R0 >> 6) & 63;
        int b  = R0 >> 12;
        int si = i - 3; si = si < 0 ? 0 : (si > 57 ? 57 : si);
        int sjm = j0 - 3; sjm = sjm < 0 ? 0 : (sjm > 57 ? 57 : sjm);
        sjm &= ~1;                      // even for 8B-aligned vbT loads
        int oi = si - i + 6;
        int jq = j0 + q;
        int sjq = jq - 3; sjq = sjq < 0 ? 0 : (sjq > 57 ? 57 : sjq);
        int lo = sjq - sjm;
        int ojq = sjm - jq + 6;
        int rb0 = (b * 64 + si) * 64;

        bf16x8 qf = *(const bf16x8*)(qb + ((size_t)h * NT + R0 + q) * HD + kg * 8);
        const __hip_bfloat16* kb_h = kb + (size_t)h * NT * HD;

        // S^T = K·Q^T : 14 tiles of 16 keys (32-col padded union, 7 rows)
        f32x4 s[14];
        #pragma unroll
        for (int kt = 0; kt < 14; ++kt) {
            const int a = kt >> 1;
            const int cb = (kt & 1) * 16;
            int col = q + cb + sjm; col = col > 63 ? 63 : col;
            int tok = rb0 + a * 64 + col;
            bf16x8 kf = *(const bf16x8*)(kb_h + (size_t)tok * HD + kg * 8);
            f32x4 z = {0.f, 0.f, 0.f, 0.f};
            s[kt] = __builtin_amdgcn_mfma_f32_16x16x32_bf16(kf, qf, z, 0, 0, 0);
        }
        // mask + bias (log2-domain) + row max
        const float* rb_h = rpbs + 16 + h * 169 + oi * 13;
        float m = -1e30f;
        #pragma unroll
        for (int kt = 0; kt < 14; ++kt) {
            const int a = kt >> 1;
            const int cb = (kt & 1) * 16;
            const float* bp = rb_h + a * 13 + (ojq + cb + kg * 4);
            #pragma unroll
            for (int r = 0; r < 4; ++r) {
                int c = cb + kg * 4 + r;
                bool valid = (unsigned)(c - lo) < 7u;
                float z = s[kt][r] * 0.25506948f + bp[r];   // (1/sqrt32)*log2e
                s[kt][r] = valid ? z : -1e30f;
                m = fmaxf(m, s[kt][r]);
            }
        }
        m = fmaxf(m, __shfl_xor(m, 16));
        m = fmaxf(m, __shfl_xor(m, 32));

        // P = exp2(S-m); O^T = V^T·P^T via 16x16x16 (zero-shuffle: P is lane-local)
        float l = 0.0f;
        f32x4 o0 = {0.f,0.f,0.f,0.f}, o1 = {0.f,0.f,0.f,0.f};
        const __hip_bfloat16* vt_l = vbT + ((size_t)(h * 32) + q) * NT;
        #pragma unroll
        for (int kt = 0; kt < 14; ++kt) {
            const int a = kt >> 1;
            const int cb = (kt & 1) * 16;
            bf16x4 pb;
            #pragma unroll
            for (int r = 0; r < 4; ++r) {
                float p = exp2f(s[kt][r] - m);
                l += p;
                pb[r] = f2bs(p);
            }
            int colb = cb + kg * 4 + sjm; colb = colb > 60 ? 60 : colb;
            int tokb = rb0 + a * 64 + colb;
            bf16x4 v0 = *(const bf16x4*)(vt_l + tokb);
            bf16x4 v1 = *(const bf16x4*)(vt_l + (size_t)16 * NT + tokb);
            o0 = mfma16(v0, pb, o0);
            o1 = mfma16(v1, pb, o1);
        }
        l += __shfl_xor(l, 16);
        l += __shfl_xor(l, 32);
        float inv = 1.0f / l;

        // write O^T: lane (kg,q) holds d = mt*16 + kg*4 + r for token q
        #pragma unroll
        for (int mt = 0; mt < 2; ++mt) {
            f32x4 ov = mt ? o1 : o0;
            ushort4 u;
            u.x = (unsigned short)f2bs(ov[0] * inv);
            u.y = (unsigned short)f2bs(ov[1] * inv);
            u.z = (unsigned short)f2bs(ov[2] * inv);
            u.w = (unsigned short)f2bs(ov[3] * inv);
            int cch = h * 4 + mt * 2 + (kg >> 1);
            ysA4[q * 32 + ((cch ^ q) << 1) + (kg & 1)] = u;
        }
    }
    __syncthreads();

    // ---- Phase B: proj (wave w covers 16 cols), K=128 from LDS attn tile -------
    {
        const bf16x8* ysA8 = (const bf16x8*)ysA4;
        bf16x8 a[4];
        #pragma unroll
        for (int t = 0; t < 4; ++t)
            a[t] = ysA8[rowf * 16 + ((t * 4 + kg) ^ rowf)];
        int col = wid * 16 + rowf;
        bf16x8 bfr[4];
        #pragma unroll
        for (int t = 0; t < 4; ++t)
            bfr[t] = *(const bf16x8*)(proj_wt + (size_t)col * CC + t * 32 + kg * 8);
        f32x4 acc = {};
        #pragma unroll
        for (int t = 0; t < 4; ++t)
            acc = __builtin_amdgcn_mfma_f32_16x16x32_bf16(a[t], bfr[t], acc, 0, 0, 0);
        float bv = proj_b[col];
        #pragma unroll
        for (int r = 0; r < 4; ++r) {
            int row = kg * 4 + r;
            x1s[row * X1P + col] = acc[r] + bv + x[(size_t)(R0 + row) * CC + col];
        }
    }
    __syncthreads();

    // ---- Phase C: LN2 (32 threads/row) -> ysA4 (reused) ------------------------
    {
        int row = tid >> 5, t32 = tid & 31;
        float4 a0 = *(const float4*)&x1s[row * X1P + t32 * 4];
        float s1 = a0.x + a0.y + a0.z + a0.w;
        float s2 = a0.x*a0.x + a0.y*a0.y + a0.z*a0.z + a0.w*a0.w;
        #pragma unroll
        for (int off = 1; off <= 16; off <<= 1) { s1 += __shfl_xor(s1, off); s2 += __shfl_xor(s2, off); }
        float mean = s1 * (1.0f / CC);
        float var  = s2 * (1.0f / CC) - mean * mean;
        float rstd = rsqrtf(var + 1e-5f);
        float4 g0 = *(const float4*)(n2g + t32 * 4);
        float4 b0 = *(const float4*)(n2b + t32 * 4);
        ushort4 ch;
        ch.x = (unsigned short)f2bs((a0.x - mean) * rstd * g0.x + b0.x);
        ch.y = (unsigned short)f2bs((a0.y - mean) * rstd * g0.y + b0.y);
        ch.z = (unsigned short)f2bs((a0.z - mean) * rstd * g0.z + b0.z);
        ch.w = (unsigned short)f2bs((a0.w - mean) * rstd * g0.w + b0.w);
        int c = t32 >> 1;
        ysA4[row * 32 + ((c ^ row) << 1) + (t32 & 1)] = ch;
    }
    __syncthreads();

    // ---- Phase D: FC1 + gelu (wave w covers 64 cols) ---------------------------
    {
        const bf16x8* ys8 = (const bf16x8*)ysA4;
        bf16x8 a[4];
        #pragma unroll
        for (int t = 0; t < 4; ++t) a[t] = ys8[rowf * 16 + ((t * 4 + kg) ^ rowf)];
        int n0 = wid * 64;
        f32x4 acc4[4] = {};
        #pragma unroll
        for (int nf = 0; nf < 4; ++nf) {
            int col = n0 + nf * 16 + rowf;
            bf16x8 bfr[4];
            #pragma unroll
            for (int t = 0; t < 4; ++t)
                bfr[t] = *(const bf16x8*)(fc1_wt + (size_t)col * CC + t * 32 + kg * 8);
            #pragma unroll
            for (int t = 0; t < 4; ++t)
                acc4[nf] = __builtin_amdgcn_mfma_f32_16x16x32_bf16(a[t], bfr[t], acc4[nf], 0, 0, 0);
        }
        #pragma unroll
        for (int nf = 0; nf < 4; ++nf) {
            int col = n0 + nf * 16 + rowf;
            float bv = fc1_b[col];
            #pragma unroll
            for (int r = 0; r < 4; ++r) {
                int row = kg * 4 + r;
                float v = acc4[nf][r] + bv;
                v = 0.5f * v * (1.0f + erff(v * 0.70710678118654752f));
                h1s[row * H1P + col] = f2bs(v);
            }
        }
    }
    __syncthreads();

    // ---- Phase E: FC2 + resid (wave w covers 16 cols), K=512 from LDS ----------
    {
        int col = wid * 16 + rowf;
        f32x4 acc = {};
        #pragma unroll
        for (int kc = 0; kc < 512; kc += 128) {
            bf16x8 a[4], bfr[4];
            #pragma unroll
            for (int t = 0; t < 4; ++t)
                a[t] = *(const bf16x8*)&h1s[rowf * H1P + kc + t * 32 + kg * 8];
            #pragma unroll
            for (int t = 0; t < 4; ++t)
                bfr[t] = *(const bf16x8*)(fc2_wt + (size_t)col * HID + kc + t * 32 + kg * 8);
            #pragma unroll
            for (int t = 0; t < 4; ++t)
                acc = __builtin_amdgcn_mfma_f32_16x16x32_bf16(a[t], bfr[t], acc, 0, 0, 0);
        }
        float bv = fc2_b[col];
        #pragma unroll
        for (int r = 0; r < 4; ++r) {
            int row = kg * 4 + r;
            out[(size_t)(R0 + row) * CC + col] = acc[r] + bv + x1s[row * X1P + col];
        }
    }
}

extern "C" void kernel_launch(void* const* d_in, const int* in_sizes, int n_in,
                              void* d_out, int out_size, void* d_ws, size_t ws_size,
                              hipStream_t stream) {
    const float* x       = (const float*)d_in[0];
    const float* norm1_g = (const float*)d_in[1];
    const float* norm1_b = (const float*)d_in[2];
    const float* qkv_w   = (const float*)d_in[3];
    const float* qkv_b   = (const float*)d_in[4];
    const float* rpb     = (const float*)d_in[5];
    const float* proj_w  = (const float*)d_in[6];
    const float* proj_b  = (const float*)d_in[7];
    const float* norm2_g = (const float*)d_in[8];
    const float* norm2_b = (const float*)d_in[9];
    const float* fc1_w   = (const float*)d_in[10];
    const float* fc1_b   = (const float*)d_in[11];
    const float* fc2_w   = (const float*)d_in[12];
    const float* fc2_b   = (const float*)d_in[13];
    float* out = (float*)d_out;
    char* ws = (char*)d_ws;

    // workspace: qb [4][8192][32], kb [4][8192][32], vbT [128][8192] (2MB each)
    __hip_bfloat16* qb  = (__hip_bfloat16*)(ws);
    __hip_bfloat16* kb  = (__hip_bfloat16*)(ws + 2097152);
    __hip_bfloat16* vbT = (__hip_bfloat16*)(ws + 4194304);
    __hip_bfloat16* qkv_wt  = (__hip_bfloat16*)(ws + 6291456);  // 384x128
    __hip_bfloat16* proj_wt = qkv_wt + 384 * 128;               // 128x128
    __hip_bfloat16* fc1_wt  = proj_wt + 128 * 128;              // 512x128
    __hip_bfloat16* fc2_wt  = fc1_wt + 512 * 128;               // 128x512

    prep_cast<<<768, 256, 0, stream>>>(qkv_w, proj_w, fc1_w, fc2_w,
                                       qkv_wt, proj_wt, fc1_wt, fc2_wt);
    qkv_ln_kernel<<<NT / 16, 512, 0, stream>>>(x, norm1_g, norm1_b, qkv_wt, qkv_b,
                                               qb, kb, vbT);
    mega_tail<<<NT / 16, 512, 0, stream>>>(qb, kb, vbT, rpb, x, proj_wt, proj_b,
                                           norm2_g, norm2_b, fc1_wt, fc1_b,
                                           fc2_wt, fc2_b, out);
}

// Round 12
// 53.684 us; speedup vs baseline: 8.1723x; 1.0011x over previous
//
#include <hip/hip_runtime.h>
#include <hip/hip_bf16.h>
#include <math.h>

// Problem constants
#define BB 2
#define HH 64
#define WW 64
#define CC 128
#define NHD 4
#define HD 32
#define KS 7
#define KK 49
#define HID 512
#define NT (BB*HH*WW)   // 8192 tokens

typedef __attribute__((ext_vector_type(8))) short bf16x8;
typedef __attribute__((ext_vector_type(4))) short bf16x4;
typedef __attribute__((ext_vector_type(4))) float f32x4;

__device__ __forceinline__ short f2bs(float v) {
    __hip_bfloat16 h = __float2bfloat16(v);
    return *reinterpret_cast<short*>(&h);
}

__device__ __forceinline__ f32x4 mfma16(bf16x4 a, bf16x4 b, f32x4 c) {
#if __has_builtin(__builtin_amdgcn_mfma_f32_16x16x16bf16_1k)
    return __builtin_amdgcn_mfma_f32_16x16x16bf16_1k(a, b, c, 0, 0, 0);
#else
    asm("v_mfma_f32_16x16x16_bf16 %0, %1, %2, %0" : "+v"(c) : "v"(a), "v"(b));
    return c;
#endif
}

// ---------------- prep: weight cast/transpose W[K][N] f32 -> Wt[N][K] bf16 ------
__global__ void prep_cast(const float* __restrict__ qkv_w, const float* __restrict__ proj_w,
                          const float* __restrict__ fc1_w, const float* __restrict__ fc2_w,
                          __hip_bfloat16* __restrict__ qkv_wt, __hip_bfloat16* __restrict__ proj_wt,
                          __hip_bfloat16* __restrict__ fc1_wt, __hip_bfloat16* __restrict__ fc2_wt) {
    int idx = blockIdx.x * 256 + threadIdx.x;
    const float* W; __hip_bfloat16* Wt; int K, N, off;
    if (idx < 49152)       { W = qkv_w;  Wt = qkv_wt;  K = 128; N = 384; off = idx; }
    else if (idx < 65536)  { W = proj_w; Wt = proj_wt; K = 128; N = 128; off = idx - 49152; }
    else if (idx < 131072) { W = fc1_w;  Wt = fc1_wt;  K = 128; N = 512; off = idx - 65536; }
    else                   { W = fc2_w;  Wt = fc2_wt;  K = 512; N = 128; off = idx - 131072; }
    int k = off / N, n = off - k * N;
    Wt[(size_t)n * K + k] = __float2bfloat16(W[(size_t)k * N + n]);
}

// ---------------- LN1 + QKV GEMM: 16 rows/block, 8 waves (48 cols each) ---------
// q,k: token-major [h][tok][32]; v: d-major vbT[h*32+d][tok].
__global__ void __launch_bounds__(512, 4)
qkv_ln_kernel(const float* __restrict__ x, const float* __restrict__ g,
              const float* __restrict__ bta, const __hip_bfloat16* __restrict__ qkv_wt,
              const float* __restrict__ qkv_b,
              __hip_bfloat16* __restrict__ qb, __hip_bfloat16* __restrict__ kb,
              __hip_bfloat16* __restrict__ vbT) {
    __shared__ ushort4 ys4[16 * 32];
    int tid = threadIdx.x;
    int R0 = blockIdx.x * 16;

    { // LN1: 32 threads per row, 4 f32 each
        int row = tid >> 5, t32 = tid & 31;
        const float* xr = x + (size_t)(R0 + row) * CC + t32 * 4;
        float4 a0 = *(const float4*)xr;
        float s1 = a0.x + a0.y + a0.z + a0.w;
        float s2 = a0.x*a0.x + a0.y*a0.y + a0.z*a0.z + a0.w*a0.w;
        #pragma unroll
        for (int off = 1; off <= 16; off <<= 1) { s1 += __shfl_xor(s1, off); s2 += __shfl_xor(s2, off); }
        float mean = s1 * (1.0f / CC);
        float var  = s2 * (1.0f / CC) - mean * mean;
        float rstd = rsqrtf(var + 1e-5f);
        float4 g0 = *(const float4*)(g + t32 * 4);
        float4 b0 = *(const float4*)(bta + t32 * 4);
        ushort4 ch;
        ch.x = (unsigned short)f2bs((a0.x - mean) * rstd * g0.x + b0.x);
        ch.y = (unsigned short)f2bs((a0.y - mean) * rstd * g0.y + b0.y);
        ch.z = (unsigned short)f2bs((a0.z - mean) * rstd * g0.z + b0.z);
        ch.w = (unsigned short)f2bs((a0.w - mean) * rstd * g0.w + b0.w);
        int c = t32 >> 1;
        ys4[row * 32 + ((c ^ row) << 1) + (t32 & 1)] = ch;
    }
    __syncthreads();

    const bf16x8* ys8 = (const bf16x8*)ys4;
    int wid = tid >> 6, lane = tid & 63;
    int rowf = lane & 15, kg = lane >> 4;
    int n0 = wid * 48;

    bf16x8 a[4];
    #pragma unroll
    for (int t = 0; t < 4; ++t) a[t] = ys8[rowf * 16 + ((t * 4 + kg) ^ rowf)];

    f32x4 acc[3] = {};
    #pragma unroll
    for (int nf = 0; nf < 3; ++nf) {
        int col = n0 + nf * 16 + rowf;
        bf16x8 bfr[4];
        #pragma unroll
        for (int t = 0; t < 4; ++t)
            bfr[t] = *(const bf16x8*)(qkv_wt + (size_t)col * CC + t * 32 + kg * 8);
        #pragma unroll
        for (int t = 0; t < 4; ++t)
            acc[nf] = __builtin_amdgcn_mfma_f32_16x16x32_bf16(a[t], bfr[t], acc[nf], 0, 0, 0);
    }
    #pragma unroll
    for (int nf = 0; nf < 3; ++nf) {
        int col = n0 + nf * 16 + rowf;
        int which = col >> 7;           // 0=q,1=k,2=v (wave-uniform)
        int h = (col >> 5) & 3;
        int d = col & 31;
        float bv = qkv_b[col];
        if (which == 2) {
            ushort4 u;
            u.x = (unsigned short)f2bs(acc[nf][0] + bv);
            u.y = (unsigned short)f2bs(acc[nf][1] + bv);
            u.z = (unsigned short)f2bs(acc[nf][2] + bv);
            u.w = (unsigned short)f2bs(acc[nf][3] + bv);
            *(ushort4*)(vbT + ((size_t)(h * 32 + d) * NT + R0 + kg * 4)) = u;
        } else {
            __hip_bfloat16* dst = which == 0 ? qb : kb;
            #pragma unroll
            for (int r = 0; r < 4; ++r)
                dst[((size_t)h * NT + (R0 + kg * 4 + r)) * HD + d] = __float2bfloat16(acc[nf][r] + bv);
        }
    }
}

// ---------------- MEGA TAIL: MFMA attn (8-wave split) -> proj -> LN2 -> FC1 -> FC2
#define X1P 132          // x1s row stride (f32)
#define H1P 520          // h1s row stride (bf16)
__global__ void __launch_bounds__(512, 4)
mega_tail(const __hip_bfloat16* __restrict__ qb, const __hip_bfloat16* __restrict__ kb,
          const __hip_bfloat16* __restrict__ vbT, const float* __restrict__ rpb,
          const float* __restrict__ x,
          const __hip_bfloat16* __restrict__ proj_wt, const float* __restrict__ proj_b,
          const float* __restrict__ n2g, const float* __restrict__ n2b,
          const __hip_bfloat16* __restrict__ fc1_wt, const float* __restrict__ fc1_b,
          const __hip_bfloat16* __restrict__ fc2_wt, const float* __restrict__ fc2_b,
          float* __restrict__ out) {
    __shared__ float rpbs[720];         // 16-offset + 4*169; pre-scaled by log2e
    __shared__ ushort4 ysA4[16 * 32];   // attn out, reused for LN2 out
    __shared__ float x1s[16 * X1P];
    __shared__ short h1s[16 * H1P];
    __shared__ float mlbuf[4][2][16];   // [h][{m,l}][q] from p=1 waves
    __shared__ float obuf[4][32][17];   // [h][d][q] padded, from p=1 waves
    int tid = threadIdx.x;
    int R0 = blockIdx.x * 16;
    int wid = tid >> 6, lane = tid & 63;
    int rowf = lane & 15, kg = lane >> 4;

    for (int idx = tid; idx < NHD * 169; idx += 512) rpbs[16 + idx] = rpb[idx] * 1.4426950408889634f;
    __syncthreads();

    // ---- Phase A: MFMA attention; wave = (head h, tile-half p) -----------------
    {
        const int h = wid & 3;
        const int p = wid >> 2;
        const int q = rowf;
        int j0 = R0 & 63;
        int i  = (R0 >> 6) & 63;
        int b  = R0 >> 12;
        int si = i - 3; si = si < 0 ? 0 : (si > 57 ? 57 : si);
        int sjm = j0 - 3; sjm = sjm < 0 ? 0 : (sjm > 57 ? 57 : sjm);
        sjm &= ~1;                      // even for 8B-aligned vbT loads
        int oi = si - i + 6;
        int jq = j0 + q;
        int sjq = jq - 3; sjq = sjq < 0 ? 0 : (sjq > 57 ? 57 : sjq);
        int lo = sjq - sjm;
        int ojq = sjm - jq + 6;
        int rb0 = (b * 64 + si) * 64;

        bf16x8 qf = *(const bf16x8*)(qb + ((size_t)h * NT + R0 + q) * HD + kg * 8);
        const __hip_bfloat16* kb_h = kb + (size_t)h * NT * HD;

        // S^T = K·Q^T : this wave's 7 of 14 tiles (kt = p*7 + u)
        f32x4 s[7];
        #pragma unroll
        for (int u = 0; u < 7; ++u) {
            int kt = p * 7 + u;
            int a = kt >> 1;
            int cb = (kt & 1) * 16;
            int col = q + cb + sjm; col = col > 63 ? 63 : col;
            int tok = rb0 + a * 64 + col;
            bf16x8 kf = *(const bf16x8*)(kb_h + (size_t)tok * HD + kg * 8);
            f32x4 z = {0.f, 0.f, 0.f, 0.f};
            s[u] = __builtin_amdgcn_mfma_f32_16x16x32_bf16(kf, qf, z, 0, 0, 0);
        }
        // mask + bias (log2-domain) + local max
        const float* rb_h = rpbs + 16 + h * 169 + oi * 13;
        float m = -1e30f;
        #pragma unroll
        for (int u = 0; u < 7; ++u) {
            int kt = p * 7 + u;
            int a = kt >> 1;
            int cb = (kt & 1) * 16;
            const float* bp = rb_h + a * 13 + (ojq + cb + kg * 4);
            #pragma unroll
            for (int r = 0; r < 4; ++r) {
                int c = cb + kg * 4 + r;
                bool valid = (unsigned)(c - lo) < 7u;
                float z = s[u][r] * 0.25506948f + bp[r];   // (1/sqrt32)*log2e
                s[u][r] = valid ? z : -1e30f;
                m = fmaxf(m, s[u][r]);
            }
        }
        m = fmaxf(m, __shfl_xor(m, 16));
        m = fmaxf(m, __shfl_xor(m, 32));

        // local P = exp2(S-m); partial O^T = V^T·P^T (zero-shuffle)
        float l = 0.0f;
        f32x4 o0 = {0.f,0.f,0.f,0.f}, o1 = {0.f,0.f,0.f,0.f};
        const __hip_bfloat16* vt_l = vbT + ((size_t)(h * 32) + q) * NT;
        #pragma unroll
        for (int u = 0; u < 7; ++u) {
            int kt = p * 7 + u;
            int a = kt >> 1;
            int cb = (kt & 1) * 16;
            bf16x4 pb;
            #pragma unroll
            for (int r = 0; r < 4; ++r) {
                float pv = exp2f(s[u][r] - m);
                l += pv;
                pb[r] = f2bs(pv);
            }
            int colb = cb + kg * 4 + sjm; colb = colb > 60 ? 60 : colb;
            int tokb = rb0 + a * 64 + colb;
            bf16x4 v0 = *(const bf16x4*)(vt_l + tokb);
            bf16x4 v1 = *(const bf16x4*)(vt_l + (size_t)16 * NT + tokb);
            o0 = mfma16(v0, pb, o0);
            o1 = mfma16(v1, pb, o1);
        }
        l += __shfl_xor(l, 16);
        l += __shfl_xor(l, 32);

        if (p == 1) {
            if (kg == 0) { mlbuf[h][0][q] = m; mlbuf[h][1][q] = l; }
            #pragma unroll
            for (int r = 0; r < 4; ++r) {
                obuf[h][kg * 4 + r][q]      = o0[r];
                obuf[h][16 + kg * 4 + r][q] = o1[r];
            }
        }
        __syncthreads();
        if (p == 0) {
            float m1 = mlbuf[h][0][q];
            float l1 = mlbuf[h][1][q];
            float M  = fmaxf(m, m1);
            float e0 = exp2f(m - M);
            float e1 = exp2f(m1 - M);
            float inv = 1.0f / (l * e0 + l1 * e1);
            #pragma unroll
            for (int mt = 0; mt < 2; ++mt) {
                f32x4 ov = mt ? o1 : o0;
                ushort4 u4;
                float v0 = (ov[0] * e0 + obuf[h][mt * 16 + kg * 4 + 0][q] * e1) * inv;
                float v1 = (ov[1] * e0 + obuf[h][mt * 16 + kg * 4 + 1][q] * e1) * inv;
                float v2 = (ov[2] * e0 + obuf[h][mt * 16 + kg * 4 + 2][q] * e1) * inv;
                float v3 = (ov[3] * e0 + obuf[h][mt * 16 + kg * 4 + 3][q] * e1) * inv;
                u4.x = (unsigned short)f2bs(v0);
                u4.y = (unsigned short)f2bs(v1);
                u4.z = (unsigned short)f2bs(v2);
                u4.w = (unsigned short)f2bs(v3);
                int cch = h * 4 + mt * 2 + (kg >> 1);
                ysA4[q * 32 + ((cch ^ q) << 1) + (kg & 1)] = u4;
            }
        }
    }
    __syncthreads();

    // ---- Phase B: proj (wave w covers 16 cols), K=128 from LDS attn tile -------
    {
        const bf16x8* ysA8 = (const bf16x8*)ysA4;
        bf16x8 a[4];
        #pragma unroll
        for (int t = 0; t < 4; ++t)
            a[t] = ysA8[rowf * 16 + ((t * 4 + kg) ^ rowf)];
        int col = wid * 16 + rowf;
        bf16x8 bfr[4];
        #pragma unroll
        for (int t = 0; t < 4; ++t)
            bfr[t] = *(const bf16x8*)(proj_wt + (size_t)col * CC + t * 32 + kg * 8);
        f32x4 acc = {};
        #pragma unroll
        for (int t = 0; t < 4; ++t)
            acc = __builtin_amdgcn_mfma_f32_16x16x32_bf16(a[t], bfr[t], acc, 0, 0, 0);
        float bv = proj_b[col];
        #pragma unroll
        for (int r = 0; r < 4; ++r) {
            int row = kg * 4 + r;
            x1s[row * X1P + col] = acc[r] + bv + x[(size_t)(R0 + row) * CC + col];
        }
    }
    __syncthreads();

    // ---- Phase C: LN2 (32 threads/row) -> ysA4 (reused) ------------------------
    {
        int row = tid >> 5, t32 = tid & 31;
        float4 a0 = *(const float4*)&x1s[row * X1P + t32 * 4];
        float s1 = a0.x + a0.y + a0.z + a0.w;
        float s2 = a0.x*a0.x + a0.y*a0.y + a0.z*a0.z + a0.w*a0.w;
        #pragma unroll
        for (int off = 1; off <= 16; off <<= 1) { s1 += __shfl_xor(s1, off); s2 += __shfl_xor(s2, off); }
        float mean = s1 * (1.0f / CC);
        float var  = s2 * (1.0f / CC) - mean * mean;
        float rstd = rsqrtf(var + 1e-5f);
        float4 g0 = *(const float4*)(n2g + t32 * 4);
        float4 b0 = *(const float4*)(n2b + t32 * 4);
        ushort4 ch;
        ch.x = (unsigned short)f2bs((a0.x - mean) * rstd * g0.x + b0.x);
        ch.y = (unsigned short)f2bs((a0.y - mean) * rstd * g0.y + b0.y);
        ch.z = (unsigned short)f2bs((a0.z - mean) * rstd * g0.z + b0.z);
        ch.w = (unsigned short)f2bs((a0.w - mean) * rstd * g0.w + b0.w);
        int c = t32 >> 1;
        ysA4[row * 32 + ((c ^ row) << 1) + (t32 & 1)] = ch;
    }
    __syncthreads();

    // ---- Phase D: FC1 + gelu (wave w covers 64 cols) ---------------------------
    {
        const bf16x8* ys8 = (const bf16x8*)ysA4;
        bf16x8 a[4];
        #pragma unroll
        for (int t = 0; t < 4; ++t) a[t] = ys8[rowf * 16 + ((t * 4 + kg) ^ rowf)];
        int n0 = wid * 64;
        f32x4 acc4[4] = {};
        #pragma unroll
        for (int nf = 0; nf < 4; ++nf) {
            int col = n0 + nf * 16 + rowf;
            bf16x8 bfr[4];
            #pragma unroll
            for (int t = 0; t < 4; ++t)
                bfr[t] = *(const bf16x8*)(fc1_wt + (size_t)col * CC + t * 32 + kg * 8);
            #pragma unroll
            for (int t = 0; t < 4; ++t)
                acc4[nf] = __builtin_amdgcn_mfma_f32_16x16x32_bf16(a[t], bfr[t], acc4[nf], 0, 0, 0);
        }
        #pragma unroll
        for (int nf = 0; nf < 4; ++nf) {
            int col = n0 + nf * 16 + rowf;
            float bv = fc1_b[col];
            #pragma unroll
            for (int r = 0; r < 4; ++r) {
                int row = kg * 4 + r;
                float v = acc4[nf][r] + bv;
                v = 0.5f * v * (1.0f + erff(v * 0.70710678118654752f));
                h1s[row * H1P + col] = f2bs(v);
            }
        }
    }
    __syncthreads();

    // ---- Phase E: FC2 + resid (wave w covers 16 cols), K=512 from LDS ----------
    {
        int col = wid * 16 + rowf;
        f32x4 acc = {};
        #pragma unroll
        for (int kc = 0; kc < 512; kc += 128) {
            bf16x8 a[4], bfr[4];
            #pragma unroll
            for (int t = 0; t < 4; ++t)
                a[t] = *(const bf16x8*)&h1s[rowf * H1P + kc + t * 32 + kg * 8];
            #pragma unroll
            for (int t = 0; t < 4; ++t)
                bfr[t] = *(const bf16x8*)(fc2_wt + (size_t)col * HID + kc + t * 32 + kg * 8);
            #pragma unroll
            for (int t = 0; t < 4; ++t)
                acc = __builtin_amdgcn_mfma_f32_16x16x32_bf16(a[t], bfr[t], acc, 0, 0, 0);
        }
        float bv = fc2_b[col];
        #pragma unroll
        for (int r = 0; r < 4; ++r) {
            int row = kg * 4 + r;
            out[(size_t)(R0 + row) * CC + col] = acc[r] + bv + x1s[row * X1P + col];
        }
    }
}

extern "C" void kernel_launch(void* const* d_in, const int* in_sizes, int n_in,
                              void* d_out, int out_size, void* d_ws, size_t ws_size,
                              hipStream_t stream) {
    const float* x       = (const float*)d_in[0];
    const float* norm1_g = (const float*)d_in[1];
    const float* norm1_b = (const float*)d_in[2];
    const float* qkv_w   = (const float*)d_in[3];
    const float* qkv_b   = (const float*)d_in[4];
    const float* rpb     = (const float*)d_in[5];
    const float* proj_w  = (const float*)d_in[6];
    const float* proj_b  = (const float*)d_in[7];
    const float* norm2_g = (const float*)d_in[8];
    const float* norm2_b = (const float*)d_in[9];
    const float* fc1_w   = (const float*)d_in[10];
    const float* fc1_b   = (const float*)d_in[11];
    const float* fc2_w   = (const float*)d_in[12];
    const float* fc2_b   = (const float*)d_in[13];
    float* out = (float*)d_out;
    char* ws = (char*)d_ws;

    // workspace: qb [4][8192][32], kb [4][8192][32], vbT [128][8192] (2MB each)
    __hip_bfloat16* qb  = (__hip_bfloat16*)(ws);
    __hip_bfloat16* kb  = (__hip_bfloat16*)(ws + 2097152);
    __hip_bfloat16* vbT = (__hip_bfloat16*)(ws + 4194304);
    __hip_bfloat16* qkv_wt  = (__hip_bfloat16*)(ws + 6291456);  // 384x128
    __hip_bfloat16* proj_wt = qkv_wt + 384 * 128;               // 128x128
    __hip_bfloat16* fc1_wt  = proj_wt + 128 * 128;              // 512x128
    __hip_bfloat16* fc2_wt  = fc1_wt + 512 * 128;               // 128x512

    prep_cast<<<768, 256, 0, stream>>>(qkv_w, proj_w, fc1_w, fc2_w,
                                       qkv_wt, proj_wt, fc1_wt, fc2_wt);
    qkv_ln_kernel<<<NT / 16, 512, 0, stream>>>(x, norm1_g, norm1_b, qkv_wt, qkv_b,
                                               qb, kb, vbT);
    mega_tail<<<NT / 16, 512, 0, stream>>>(qb, kb, vbT, rpb, x, proj_wt, proj_b,
                                           norm2_g, norm2_b, fc1_wt, fc1_b,
                                           fc2_wt, fc2_b, out);
}